// Round 9
// baseline (449.216 us; speedup 1.0000x reference)
//
#include <hip/hip_runtime.h>
#include <hip/hip_bf16.h>
#include <math.h>

// StyleGAN3 SynthesisLayer forward, MI355X.
// B=16, CIN=COUT=256, H=W=64, K=3, up=2 down=2 taps=12, conv out 66x66,
// up-FIR out 138x138, final out 64x64.

typedef __attribute__((ext_vector_type(8))) short bf16x8;
typedef __attribute__((ext_vector_type(4))) float f32x4;

#define NM 69696         // 16*66*66 flattened conv-output positions
#define SPI 4356         // 66*66 spatial per image

__device__ inline void gload16(const void* g, void* l) {
  __builtin_amdgcn_global_load_lds((const __attribute__((address_space(1))) void*)g,
                                   (__attribute__((address_space(3))) void*)l, 16, 0, 0);
}

// ---------- styles = w @ aw^T / sqrt(512) + ab ----------
__global__ __launch_bounds__(256) void k_styles(
    const float* __restrict__ w, const float* __restrict__ aw,
    const float* __restrict__ ab, float* __restrict__ styles) {
  __shared__ float lw[512];
  int b = blockIdx.x, t = threadIdx.x;
  lw[t] = w[b * 512 + t];
  lw[t + 256] = w[b * 512 + t + 256];
  __syncthreads();
  const float* row = aw + (long)t * 512;
  float acc = 0.f;
  #pragma unroll 4
  for (int d = 0; d < 512; ++d) acc += row[d] * lw[d];
  styles[b * 256 + t] = acc * 0.04419417382415922f + ab[t];
}

// ---------- scal[0] = 1/mean(styles^2), scal[1] = rsqrt(ema) ----------
__global__ __launch_bounds__(256) void k_scalars(
    const float* __restrict__ styles, const float* __restrict__ ema,
    float* __restrict__ scal) {
  __shared__ float red[256];
  int t = threadIdx.x;
  float s = 0.f;
  #pragma unroll
  for (int k = 0; k < 16; ++k) { float v = styles[t + k * 256]; s += v * v; }
  red[t] = s; __syncthreads();
  for (int off = 128; off > 0; off >>= 1) {
    if (t < off) red[t] += red[t + off];
    __syncthreads();
  }
  if (t == 0) { scal[0] = 4096.0f / red[0]; scal[1] = 1.0f / sqrtf(ema[0]); }
}

// ---------- per-o weight norm; wsq[o][i]; wbt[tap][cc][o][32ci] bf16 ----------
__global__ __launch_bounds__(256) void k_wnorm(
    const float* __restrict__ cw, float* __restrict__ wsq,
    __hip_bfloat16* __restrict__ wbt) {
  __shared__ float red[256];
  __shared__ float lws, lws2;
  int o = blockIdx.x, t = threadIdx.x;
  const float* base = cw + o * 2304;
  float s = 0.f;
  #pragma unroll
  for (int k = 0; k < 9; ++k) { float v = base[t + k * 256]; s += v * v; }
  red[t] = s; __syncthreads();
  for (int off = 128; off > 0; off >>= 1) {
    if (t < off) red[t] += red[t + off];
    __syncthreads();
  }
  if (t == 0) { lws2 = 2304.0f / red[0]; lws = sqrtf(lws2); }
  __syncthreads();
  const float* r9 = base + t * 9;
  float s9 = 0.f;
  #pragma unroll
  for (int k = 0; k < 9; ++k) s9 += r9[k] * r9[k];
  wsq[o * 256 + t] = lws2 * s9;
  int cc = t >> 5, ci = t & 31;
  #pragma unroll
  for (int tap = 0; tap < 9; ++tap)
    wbt[(((tap * 8 + cc) * 256 + o) << 5) + ci] = __float2bfloat16(r9[tap] * lws);
}

// ---------- dcoefs[b][o] = rsqrt(sum_i s^2 * wsq + 1e-8) * input_gain ----------
__global__ __launch_bounds__(256) void k_dcoefs(
    const float* __restrict__ styles, const float* __restrict__ wsq,
    const float* __restrict__ scal, float* __restrict__ dco) {
  __shared__ float sn2[256];
  int b = blockIdx.x, t = threadIdx.x;
  float v = styles[b * 256 + t];
  sn2[t] = v * v * scal[0];
  __syncthreads();
  const float* wr = wsq + t * 256;
  float acc = 0.f;
  #pragma unroll 4
  for (int i = 0; i < 256; ++i) acc += sn2[i] * wr[i];
  dco[b * 256 + t] = (1.0f / sqrtf(acc + 1e-8f)) * scal[1];
}

// ---------- xs_pad chunked: xp[b][cc=8][68*68 px][32 ci] bf16, style-scaled ----------
__global__ __launch_bounds__(256) void k_xpad(
    const float* __restrict__ x, const float* __restrict__ styles,
    const float* __restrict__ scal, unsigned short* __restrict__ xp) {
  __shared__ float lx[64 * 65];
  __shared__ float sc[64];
  int ig = blockIdx.x, hp = blockIdx.y, b = blockIdx.z, t = threadIdx.x;
  int i0 = ig * 64;
  float ss = sqrtf(scal[0]);
  if (t < 64) sc[t] = styles[b * 256 + i0 + t] * ss;
  int h = hp - 2;
  bool inh = (hp >= 2) && (hp < 66);
  if (inh) {
    #pragma unroll
    for (int p = 0; p < 16; ++p) {
      int idx = p * 256 + t; int i = idx >> 6, w = idx & 63;
      lx[i * 65 + w] = x[((b * 256 + i0 + i) * 64 + h) * 64 + w];
    }
  }
  __syncthreads();
  // dst: [b][cc][px=hp*68+wp][ci]; this block covers cc = ig*2 + {0,1}
  unsigned short* dst = xp + (((long)(b * 8 + ig * 2) * 4624 + hp * 68) << 5);
  #pragma unroll
  for (int p = 0; p < 17; ++p) {
    int idx = p * 256 + t; int wp = idx >> 6, i = idx & 63;
    float v = 0.f;
    if (inh && wp >= 2 && wp < 66) v = lx[i * 65 + (wp - 2)] * sc[i];
    __hip_bfloat16 bv = __float2bfloat16(v);
    dst[(long)(i >> 5) * 147968 + wp * 32 + (i & 31)] = *(unsigned short*)&bv;
  }
}

// ---------- conv v7: B-in-registers, barrier-light slab GEMM ----------
// Block = 256 m of ONE image x 128 o-half (576 blocks), 512 thr = 8 waves
// (4m x 2n), acc 4x4. A: per-cc contiguous 7-row slab in LDS (2x32KB dbuf,
// staged at steps 1-4 of prior cc). B: NO LDS -- each thread loads its 4
// fragment rows straight to registers (64 lanes x 16B = 1KB contiguous per
// wave; waves sharing wn hit L1), double-buffered bv0/bv1, prefetch 1 step.
// R7 diagnosis: per-step 8KB B panel missed L2 (FETCH 280MB) and 144
// lockstepped barriers exposed the latency every step. Now: barriers only
// at cc-slab swaps (8 + 2), waves free-run across the 9 taps of each cc.
// cc processed in PAIRS (18 unrolled steps) so bv parity is compile-time
// static (rule #20). vmcnt(4)+barrier at each boundary retires A rounds
// (everything except the 4 just-issued B prefetch loads).
__global__ __launch_bounds__(512, 4) void k_conv(
    const unsigned short* __restrict__ xp, const unsigned short* __restrict__ wbt,
    const float* __restrict__ dco, const float* __restrict__ bias,
    float* __restrict__ y) {
  __shared__ __align__(16) unsigned short As[2][16384];  // 2 x 32KB
  const int t = threadIdx.x;
  const int lane = t & 63;
  const int wave = t >> 6;
  const int wm = wave >> 1, wn = wave & 1;
  const int g = lane >> 4;                 // k 16B-chunk 0..3

  // XCD swizzle: 576 = 8*72
  const int f = blockIdx.x;
  const int wgid = (f & 7) * 72 + (f >> 3);
  const int oh = wgid & 1;                 // o half (0/1)
  const int mt = wgid >> 1;                // 0..287
  const int b  = mt / 18;
  const int kt = mt - b * 18;
  const int mstart = kt * 256;             // local m start within image
  const int r0 = mstart / 66;              // first output row of tile

  // per-thread A-fragment pixel bases (slab-relative; valid m: px+koff <= 475)
  int pxbase[4];
  #pragma unroll
  for (int fm = 0; fm < 4; ++fm) {
    int m = mstart + wm * 64 + fm * 16 + (lane & 15);
    int rr = m / 66; int cc_ = m - rr * 66;
    pxbase[fm] = (rr - r0) * 68 + cc_;
  }
  f32x4 acc[4][4] = {};
  const char* xb = (const char*)xp;
  // thread's B base: panel + brow*64 + g*16, brow = wn*64 + fn*16 + (lane&15)
  const char* wbB = (const char*)wbt + oh * 8192 +
                    ((wn * 64 + (lane & 15)) << 6) + (g << 4);
  char* asb = (char*)As;

  // A-slab stage: round r (0..3) of channel-chunk ccsrc into As[dbuf].
  // Slab = rows r0..r0+6 (7x68=476 px), tasks 0..1903 (clamped dup above).
  auto stageA = [&](int ccsrc, int dbuf, int r) {
    int task = r * 512 + t;
    int ct = task > 1903 ? 1903 : task;
    int px = ct >> 2, cph = ct & 3;
    int srow = px / 68, scol = px - srow * 68;
    int row = r0 + srow; if (row > 67) row = 67;
    int csrc = cph ^ ((px >> 1) & 3);
    const char* src = xb + (((b * 8 + ccsrc) * 4624 + row * 68 + scol) << 6) + (csrc << 4);
    gload16(src, asb + (dbuf << 15) + (task << 4));
  };

  bf16x8 bv0[4], bv1[4];
  // prologue: slab cc0 + bv0 = B(tap0, cc0); full drain once
  stageA(0, 0, 0); stageA(0, 0, 1); stageA(0, 0, 2); stageA(0, 0, 3);
  #pragma unroll
  for (int fn = 0; fn < 4; ++fn)
    bv0[fn] = *(const bf16x8*)(wbB + (fn << 10));
  asm volatile("s_waitcnt vmcnt(0)" ::: "memory");
  __builtin_amdgcn_s_barrier();
  __builtin_amdgcn_sched_barrier(0);

  for (int ccp = 0; ccp < 4; ++ccp) {
    #pragma unroll
    for (int s2 = 0; s2 < 18; ++s2) {
      const int cl = s2 / 9;               // static 0/1: local cc, = LDS buf
      const int tap = s2 - cl * 9;         // static 0..8
      const int cc = ccp * 2 + cl;
      // 1) prefetch next step's B fragments into the alternate bv bank
      {
        const int tapn = (tap == 8) ? 0 : tap + 1;     // static
        int ccn = (tap == 8) ? (cc == 7 ? 0 : cc + 1) : cc;
        const char* pbp = wbB + ((tapn * 8 + ccn) << 14);
        if ((s2 & 1) == 0) {
          #pragma unroll
          for (int fn = 0; fn < 4; ++fn) bv1[fn] = *(const bf16x8*)(pbp + (fn << 10));
        } else {
          #pragma unroll
          for (int fn = 0; fn < 4; ++fn) bv0[fn] = *(const bf16x8*)(pbp + (fn << 10));
        }
      }
      // 2) A-slab rounds for the NEXT cc (>=5 steps of slack)
      if (s2 >= 1 && s2 <= 4) {
        stageA(ccp * 2 + 1, 1, s2 - 1);
      } else if (s2 >= 10 && s2 <= 13) {
        int nsrc = ccp * 2 + 2;            // ccp=3 -> 8: dummy restage of cc0
        stageA(nsrc == 8 ? 0 : nsrc, 0, s2 - 10);
      }
      // 3) compute (bv bank of THIS step is static: even s2 -> bv0)
      {
        const char* abuf = asb + (cl << 15);
        const int koff = (tap / 3) * 68 + (tap % 3);   // compile-time
        bf16x8 av[4];
        #pragma unroll
        for (int fm = 0; fm < 4; ++fm) {
          int px = pxbase[fm] + koff;
          int slot = (px << 2) + (g ^ ((px >> 1) & 3));
          av[fm] = *(const bf16x8*)(abuf + (slot << 4));
        }
        __builtin_amdgcn_s_setprio(1);
        if ((s2 & 1) == 0) {
          #pragma unroll
          for (int fm = 0; fm < 4; ++fm)
            #pragma unroll
            for (int fn = 0; fn < 4; ++fn)
              acc[fm][fn] = __builtin_amdgcn_mfma_f32_16x16x32_bf16(
                  av[fm], bv0[fn], acc[fm][fn], 0, 0, 0);
        } else {
          #pragma unroll
          for (int fm = 0; fm < 4; ++fm)
            #pragma unroll
            for (int fn = 0; fn < 4; ++fn)
              acc[fm][fn] = __builtin_amdgcn_mfma_f32_16x16x32_bf16(
                  av[fm], bv1[fn], acc[fm][fn], 0, 0, 0);
        }
        __builtin_amdgcn_s_setprio(0);
      }
      // 4) cc-boundary: slab swap. Retire everything except the 4 B
      // prefetch loads just issued; then barrier + pin.
      if (tap == 8) {
        asm volatile("s_waitcnt vmcnt(4)" ::: "memory");
        __builtin_amdgcn_s_barrier();
        __builtin_amdgcn_sched_barrier(0);
      }
    }
  }
  asm volatile("s_waitcnt vmcnt(0)" ::: "memory");
  __builtin_amdgcn_s_barrier();

  // Epilogue: scale + bias, transpose via LDS slab [256m][17], write NCHW.
  float* slab = (float*)As;
  const float* dcrow = dco + b * 256 + oh * 128;
  #pragma unroll
  for (int s = 0; s < 8; ++s) {
    if (wn == (s >> 2)) {
      const int sfn = s & 3;
      int ocol = lane & 15;
      float bo = bias[oh * 128 + s * 16 + ocol];
      float dc = dcrow[s * 16 + ocol];
      #pragma unroll
      for (int fm = 0; fm < 4; ++fm) {
        #pragma unroll
        for (int j = 0; j < 4; ++j) {
          int lm = wm * 64 + fm * 16 + ((lane >> 4) << 2) + j;
          slab[lm * 17 + ocol] = acc[fm][sfn][j] * dc + bo;
        }
      }
    }
    __syncthreads();
    int oc2 = t >> 5;                       // 0..15
    int og2 = oh * 128 + s * 16 + oc2;
    #pragma unroll
    for (int p = 0; p < 8; ++p) {
      int lm = (t & 31) + p * 32;
      int sp = mstart + lm;
      if (sp < SPI)
        y[(long)(b * 256 + og2) * SPI + sp] = slab[lm * 17 + oc2];
    }
    __syncthreads();
  }
}

// ---------- filtered_lrelu: column-strip, vectorized LDS ----------
struct Filt { float f[12]; };

__global__ __launch_bounds__(256) void k_lrelu(
    const float* __restrict__ y, float* __restrict__ out, Filt ft) {
  __shared__ __align__(16) float t1[3864];    // [138][28]
  __shared__ __align__(16) float t2[6072];    // [138][44]
  float* bufY = t2;                           // [66][28] overlays t2
  float* t3 = t1;                             // [64][44] overlays t1
  const int t = threadIdx.x;
  const int strip = blockIdx.x & 3;
  const long img = blockIdx.x >> 2;
  const int c0 = strip * 16;
  const float* ysrc = y + img * SPI;

  // phase 1: bufY[66][28], cols c0-4..c0+21 in slots 0..25, rest 0
  #pragma unroll
  for (int p = 0; p < 8; ++p) {
    int e = p * 256 + t;
    if (e < 1848) {
      int r = e / 28, lc = e - r * 28;
      int c = c0 - 4 + lc;
      bufY[e] = (lc < 26 && c >= 0 && c < 66) ? ysrc[r * 66 + c] : 0.f;
    }
  }
  __syncthreads();

  // phase 2: vertical up-FIR -> t1 [138][28], float4 col-quads
  #pragma unroll
  for (int p = 0; p < 4; ++p) {
    int e = p * 256 + t;
    if (e < 966) {                        // 138 rows x 7 quads
      int rr = e / 7, q = e - rr * 7;
      int p0 = (rr + 1) & 1;
      int yr0 = (rr + p0 - 9) >> 1;
      float4 a = make_float4(0.f, 0.f, 0.f, 0.f);
      #pragma unroll
      for (int j = 0; j < 6; ++j) {
        int yr = yr0 + j;
        if (yr >= 0 && yr < 66) {
          float cf = ft.f[2 * j + p0];
          float4 v = *(const float4*)&bufY[yr * 28 + 4 * q];
          a.x += cf * v.x; a.y += cf * v.y; a.z += cf * v.z; a.w += cf * v.w;
        }
      }
      *(float4*)&t1[rr * 28 + 4 * q] =
          make_float4(2.f * a.x, 2.f * a.y, 2.f * a.z, 2.f * a.w);
    }
  }
  __syncthreads();

  // phase 3: horizontal up-FIR + lrelu*sqrt2 + clamp -> t2 [138][44]
  #pragma unroll
  for (int p = 0; p < 6; ++p) {
    int e = p * 256 + t;
    if (e < 1518) {                       // 138 rows x 11 quads
      int rr = e / 11, v = e - rr * 11;
      const float* tr = t1 + rr * 28 + 2 * v;
      float2 w0 = *(const float2*)(tr + 0);
      float2 w1 = *(const float2*)(tr + 2);
      float2 w2 = *(const float2*)(tr + 4);
      float2 w3 = *(const float2*)(tr + 6);
      float w[8] = {w0.x, w0.y, w1.x, w1.y, w2.x, w2.y, w3.x, w3.y};
      float a0 = 0.f, a1 = 0.f, a2 = 0.f, a3 = 0.f;
      #pragma unroll
      for (int j = 0; j < 6; ++j) {
        float fe = ft.f[2 * j], fo = ft.f[2 * j + 1];
        a0 += fo * w[j];
        a1 += fe * w[j];
        a2 += fo * w[j + 1];
        a3 += fe * w[j + 1];
      }
      float4 r;
      r.x = a0 * 2.f; r.y = a1 * 2.f; r.z = a2 * 2.f; r.w = a3 * 2.f;
      r.x = (r.x < 0.f ? 0.2f * r.x : r.x) * 1.41421356237f;
      r.y = (r.y < 0.f ? 0.2f * r.y : r.y) * 1.41421356237f;
      r.z = (r.z < 0.f ? 0.2f * r.z : r.z) * 1.41421356237f;
      r.w = (r.w < 0.f ? 0.2f * r.w : r.w) * 1.41421356237f;
      r.x = fminf(fmaxf(r.x, -256.f), 256.f);
      r.y = fminf(fmaxf(r.y, -256.f), 256.f);
      r.z = fminf(fmaxf(r.z, -256.f), 256.f);
      r.w = fminf(fmaxf(r.w, -256.f), 256.f);
      *(float4*)&t2[rr * 44 + 4 * v] = r;
    }
  }
  __syncthreads();

  // phase 4: vertical down-FIR (stride 2) -> t3 [64][44], float4 quads
  #pragma unroll
  for (int p = 0; p < 3; ++p) {
    int e = p * 256 + t;
    if (e < 704) {                        // 64 rows x 11 quads
      int pp = e / 11, v = e - pp * 11;
      const float* col = t2 + (2 * pp) * 44 + 4 * v;
      float4 a = make_float4(0.f, 0.f, 0.f, 0.f);
      #pragma unroll
      for (int j = 0; j < 12; ++j) {
        float cf = ft.f[j];
        float4 x4 = *(const float4*)&col[j * 44];
        a.x += cf * x4.x; a.y += cf * x4.y; a.z += cf * x4.z; a.w += cf * x4.w;
      }
      *(float4*)&t3[pp * 44 + 4 * v] = a;
    }
  }
  __syncthreads();

  // phase 5: horizontal down-FIR (stride 2) + store, 4 outs/thread
  {
    int pp = t >> 2, v = t & 3;           // 64 rows x 4 quads = 256 tasks
    const float* row = t3 + pp * 44 + 8 * v;
    float w[20];
    #pragma unroll
    for (int k = 0; k < 5; ++k) {
      float4 x4 = *(const float4*)&row[4 * k];
      w[4 * k] = x4.x; w[4 * k + 1] = x4.y; w[4 * k + 2] = x4.z; w[4 * k + 3] = x4.w;
    }
    float a0 = 0.f, a1 = 0.f, a2 = 0.f, a3 = 0.f;
    #pragma unroll
    for (int j = 0; j < 12; ++j) {
      float cf = ft.f[j];
      a0 += cf * w[j]; a1 += cf * w[j + 2]; a2 += cf * w[j + 4]; a3 += cf * w[j + 6];
    }
    *(float4*)&out[img * 4096 + pp * 64 + c0 + 4 * v] = make_float4(a0, a1, a2, a3);
  }
}

// ---------- host ----------
static double bessel_i0(double x) {
  double q = x * x * 0.25, term = 1.0, sum = 1.0;
  for (int k = 1; k < 64; ++k) {
    term *= q / ((double)k * (double)k);
    sum += term;
    if (term < sum * 1e-18) break;
  }
  return sum;
}

extern "C" void kernel_launch(void* const* d_in, const int* in_sizes, int n_in,
                              void* d_out, int out_size, void* d_ws, size_t ws_size,
                              hipStream_t stream) {
  const float* x   = (const float*)d_in[0];
  const float* w   = (const float*)d_in[1];
  const float* aw  = (const float*)d_in[2];
  const float* ab  = (const float*)d_in[3];
  const float* cw  = (const float*)d_in[4];
  const float* cb  = (const float*)d_in[5];
  const float* ema = (const float*)d_in[6];
  float* out = (float*)d_out;
  char* ws = (char*)d_ws;

  float* styles        = (float*)(ws + 0);          // 16 KB
  float* scal          = (float*)(ws + 16384);      // 16 B
  float* wsq           = (float*)(ws + 16640);      // 256 KB
  float* dco           = (float*)(ws + 278784);     // 16 KB
  __hip_bfloat16* wbt  = (__hip_bfloat16*)(ws + 295168);   // 1.18 MB  [9][8cc][256o][32ci]
  unsigned short* xp   = (unsigned short*)(ws + 1474816);  // 37.9 MB  [16][8cc][68*68][32ci]
  float* y             = (float*)(ws + 39354624);   // 71.4 MB  [16][256][66][66]

  // firwin(12, 16, width=32, fs=128) with Kaiser window (double precision)
  Filt ft;
  {
    double atten = 2.285 * 11.0 * M_PI * 0.5 + 7.95;
    double beta;
    if (atten > 50.0) beta = 0.1102 * (atten - 8.7);
    else if (atten > 21.0) beta = 0.5842 * pow(atten - 21.0, 0.4) + 0.07886 * (atten - 21.0);
    else beta = 0.0;
    double i0b = bessel_i0(beta);
    double h[12], ssum = 0.0;
    for (int n = 0; n < 12; ++n) {
      double xx = ((double)n - 5.5) / 5.5;
      double win = bessel_i0(beta * sqrt(1.0 - xx * xx)) / i0b;
      double mm = ((double)n - 5.5) * 0.25;
      double snc = sin(M_PI * mm) / (M_PI * mm);
      h[n] = 0.25 * snc * win;
      ssum += h[n];
    }
    for (int n = 0; n < 12; ++n) ft.f[n] = (float)(h[n] / ssum);
  }

  k_styles <<<16, 256, 0, stream>>>(w, aw, ab, styles);
  k_scalars<<<1, 256, 0, stream>>>(styles, ema, scal);
  k_wnorm  <<<256, 256, 0, stream>>>(cw, wsq, wbt);
  k_dcoefs <<<16, 256, 0, stream>>>(styles, wsq, scal, dco);
  k_xpad   <<<dim3(4, 68, 16), 256, 0, stream>>>(x, styles, scal, xp);
  k_conv   <<<576, 512, 0, stream>>>(xp, (const unsigned short*)wbt, dco, cb, y);
  k_lrelu  <<<16384, 256, 0, stream>>>(y, out, ft);
}

// Round 10
// 365.066 us; speedup vs baseline: 1.2305x; 1.2305x over previous
//
#include <hip/hip_runtime.h>
#include <hip/hip_bf16.h>
#include <math.h>

// StyleGAN3 SynthesisLayer forward, MI355X.
// B=16, CIN=COUT=256, H=W=64, K=3, up=2 down=2 taps=12, conv out 66x66,
// up-FIR out 138x138, final out 64x64.

typedef __attribute__((ext_vector_type(8))) short bf16x8;
typedef __attribute__((ext_vector_type(4))) short short4v;
typedef __attribute__((ext_vector_type(4))) float f32x4;

#define NM 69696         // 16*66*66 flattened conv-output positions
#define SPI 4356         // 66*66 spatial per image

__device__ inline void gload16(const void* g, void* l) {
  __builtin_amdgcn_global_load_lds((const __attribute__((address_space(1))) void*)g,
                                   (__attribute__((address_space(3))) void*)l, 16, 0, 0);
}
static __device__ __forceinline__ float bf2f(short h) {
  union { unsigned u; float f; } c;
  c.u = ((unsigned)(unsigned short)h) << 16;
  return c.f;
}
static __device__ __forceinline__ short f2bs(float f) {
  __hip_bfloat16 h = __float2bfloat16(f);
  return *(short*)&h;
}

// ---------- styles = w @ aw^T / sqrt(512) + ab ----------
__global__ __launch_bounds__(256) void k_styles(
    const float* __restrict__ w, const float* __restrict__ aw,
    const float* __restrict__ ab, float* __restrict__ styles) {
  __shared__ float lw[512];
  int b = blockIdx.x, t = threadIdx.x;
  lw[t] = w[b * 512 + t];
  lw[t + 256] = w[b * 512 + t + 256];
  __syncthreads();
  const float* row = aw + (long)t * 512;
  float acc = 0.f;
  #pragma unroll 4
  for (int d = 0; d < 512; ++d) acc += row[d] * lw[d];
  styles[b * 256 + t] = acc * 0.04419417382415922f + ab[t];
}

// ---------- scal[0] = 1/mean(styles^2), scal[1] = rsqrt(ema) ----------
__global__ __launch_bounds__(256) void k_scalars(
    const float* __restrict__ styles, const float* __restrict__ ema,
    float* __restrict__ scal) {
  __shared__ float red[256];
  int t = threadIdx.x;
  float s = 0.f;
  #pragma unroll
  for (int k = 0; k < 16; ++k) { float v = styles[t + k * 256]; s += v * v; }
  red[t] = s; __syncthreads();
  for (int off = 128; off > 0; off >>= 1) {
    if (t < off) red[t] += red[t + off];
    __syncthreads();
  }
  if (t == 0) { scal[0] = 4096.0f / red[0]; scal[1] = 1.0f / sqrtf(ema[0]); }
}

// ---------- per-o weight norm; wsq[o][i]; wbt[tap][o][i] bf16 (R1 layout) ----------
__global__ __launch_bounds__(256) void k_wnorm(
    const float* __restrict__ cw, float* __restrict__ wsq,
    __hip_bfloat16* __restrict__ wbt) {
  __shared__ float red[256];
  __shared__ float lws, lws2;
  int o = blockIdx.x, t = threadIdx.x;
  const float* base = cw + o * 2304;
  float s = 0.f;
  #pragma unroll
  for (int k = 0; k < 9; ++k) { float v = base[t + k * 256]; s += v * v; }
  red[t] = s; __syncthreads();
  for (int off = 128; off > 0; off >>= 1) {
    if (t < off) red[t] += red[t + off];
    __syncthreads();
  }
  if (t == 0) { lws2 = 2304.0f / red[0]; lws = sqrtf(lws2); }
  __syncthreads();
  const float* r9 = base + t * 9;
  float s9 = 0.f;
  #pragma unroll
  for (int k = 0; k < 9; ++k) s9 += r9[k] * r9[k];
  wsq[o * 256 + t] = lws2 * s9;
  #pragma unroll
  for (int tap = 0; tap < 9; ++tap)
    wbt[(tap * 256 + o) * 256 + t] = __float2bfloat16(r9[tap] * lws);
}

// ---------- dcoefs[b][o] = rsqrt(sum_i s^2 * wsq + 1e-8) * input_gain ----------
__global__ __launch_bounds__(256) void k_dcoefs(
    const float* __restrict__ styles, const float* __restrict__ wsq,
    const float* __restrict__ scal, float* __restrict__ dco) {
  __shared__ float sn2[256];
  int b = blockIdx.x, t = threadIdx.x;
  float v = styles[b * 256 + t];
  sn2[t] = v * v * scal[0];
  __syncthreads();
  const float* wr = wsq + t * 256;
  float acc = 0.f;
  #pragma unroll 4
  for (int i = 0; i < 256; ++i) acc += sn2[i] * wr[i];
  dco[b * 256 + t] = (1.0f / sqrtf(acc + 1e-8f)) * scal[1];
}

// ---------- xs_pad[b][68][68][256] bf16, NHWC, style-scaled (R1 layout) ----------
__global__ __launch_bounds__(256) void k_xpad(
    const float* __restrict__ x, const float* __restrict__ styles,
    const float* __restrict__ scal, unsigned short* __restrict__ xp) {
  __shared__ float lx[64 * 65];
  __shared__ float sc[64];
  int ig = blockIdx.x, hp = blockIdx.y, b = blockIdx.z, t = threadIdx.x;
  int i0 = ig * 64;
  float ss = sqrtf(scal[0]);
  if (t < 64) sc[t] = styles[b * 256 + i0 + t] * ss;
  int h = hp - 2;
  bool inh = (hp >= 2) && (hp < 66);
  if (inh) {
    #pragma unroll
    for (int p = 0; p < 16; ++p) {
      int idx = p * 256 + t; int i = idx >> 6, w = idx & 63;
      lx[i * 65 + w] = x[((b * 256 + i0 + i) * 64 + h) * 64 + w];
    }
  }
  __syncthreads();
  unsigned short* dst = xp + ((long)(b * 68 + hp) * 68) * 256 + i0;
  #pragma unroll
  for (int p = 0; p < 17; ++p) {
    int idx = p * 256 + t; int wp = idx >> 6, i = idx & 63;
    float v = 0.f;
    if (inh && wp >= 2 && wp < 66) v = lx[i * 65 + (wp - 2)] * sc[i];
    __hip_bfloat16 bv = __float2bfloat16(v);
    dst[wp * 256 + i] = *(unsigned short*)&bv;
  }
}

// ---------- conv: R1-proven implicit GEMM (198us), epilogue writes bf16 y ----------
// Tile BM=128 BN=128 BK=64; grid (2, 545); 256 threads = 4 waves (2x2 of 64x64).
// LDS tiles [row][8 chunks of 16B] with XOR swizzle (chunk ^= row&7), fed by
// global_load_lds w/ pre-swizzled per-lane source.
__global__ __launch_bounds__(256) void k_conv(
    const unsigned short* __restrict__ xp, const unsigned short* __restrict__ wbt,
    const float* __restrict__ dco, const float* __restrict__ bias,
    unsigned short* __restrict__ y) {
  __shared__ __align__(16) unsigned short As[128 * 64];
  __shared__ __align__(16) unsigned short Bs[128 * 64];
  const int t = threadIdx.x;
  const int lane = t & 63;
  const int wave = t >> 6;
  const int wm = wave >> 1, wn = wave & 1;
  const int o0 = blockIdx.x * 128;
  const int m0 = blockIdx.y * 128;

  int abase[4], bbase[4];
  #pragma unroll
  for (int j = 0; j < 4; ++j) {
    int task = j * 256 + t;
    int lm = task >> 3, ch = task & 7;
    int csrc = ch ^ (lm & 7);
    int m = m0 + lm; if (m > NM - 1) m = NM - 1;
    int b = m / SPI; int sp = m - b * SPI;
    int r = sp / 66; int c = sp - r * 66;
    abase[j] = (((b * 68 + r) * 68 + c) << 9) + (csrc << 4);   // bytes
    bbase[j] = ((o0 + lm) << 9) + (csrc << 4);                 // bytes
  }
  f32x4 acc[4][4] = {};
  const char* xb = (const char*)xp;
  const char* wb = (const char*)wbt;
  char* asb = (char*)As;
  char* bsb = (char*)Bs;

  for (int kk = 0; kk < 36; ++kk) {
    int tap = kk >> 2;
    int ch0b = (kk & 3) << 7;            // ch0 * 2 bytes
    int ky = tap / 3, kx = tap - ky * 3;
    int aoff = ((ky * 68 + kx) << 9) + ch0b;
    int boff = (tap << 17) + ch0b;
    #pragma unroll
    for (int j = 0; j < 4; ++j) {
      gload16(xb + abase[j] + aoff, asb + ((j * 256 + t) << 4));
      gload16(wb + bbase[j] + boff, bsb + ((j * 256 + t) << 4));
    }
    __syncthreads();   // drains vmcnt -> tiles visible
    #pragma unroll
    for (int h = 0; h < 2; ++h) {
      bf16x8 av[4], bv[4];
      #pragma unroll
      for (int fm = 0; fm < 4; ++fm) {
        int arow = wm * 64 + fm * 16 + (lane & 15);
        int chk = ((h << 2) + (lane >> 4)) ^ (arow & 7);
        av[fm] = *(const bf16x8*)(asb + arow * 128 + chk * 16);
      }
      #pragma unroll
      for (int fn = 0; fn < 4; ++fn) {
        int brow = wn * 64 + fn * 16 + (lane & 15);
        int chk = ((h << 2) + (lane >> 4)) ^ (brow & 7);
        bv[fn] = *(const bf16x8*)(bsb + brow * 128 + chk * 16);
      }
      #pragma unroll
      for (int fm = 0; fm < 4; ++fm)
        #pragma unroll
        for (int fn = 0; fn < 4; ++fn)
          acc[fm][fn] = __builtin_amdgcn_mfma_f32_16x16x32_bf16(
              av[fm], bv[fn], acc[fm][fn], 0, 0, 0);
    }
    __syncthreads();   // readers done before next overwrite
  }

  // Epilogue: scale + bias, transpose via LDS slab [128m][17], write NCHW bf16.
  float* slab = (float*)As;
  #pragma unroll
  for (int s = 0; s < 8; ++s) {
    if (wn == (s >> 2)) {
      const int sfn = s & 3;
      int ocol = lane & 15;
      int og = o0 + s * 16 + ocol;
      float bo = bias[og];
      #pragma unroll
      for (int fm = 0; fm < 4; ++fm) {
        #pragma unroll
        for (int j = 0; j < 4; ++j) {
          int lm = wm * 64 + fm * 16 + ((lane >> 4) << 2) + j;
          int m = m0 + lm;
          float v = acc[fm][sfn][j];
          if (m < NM) {
            int b = m / SPI;
            v = v * dco[b * 256 + og] + bo;
          }
          slab[lm * 17 + ocol] = v;
        }
      }
    }
    __syncthreads();
    int oc2 = t >> 4;
    int og2 = o0 + s * 16 + oc2;
    #pragma unroll
    for (int p = 0; p < 8; ++p) {
      int lm = (t & 15) + p * 16;
      int m = m0 + lm;
      if (m < NM) {
        int b = m / SPI; int sp = m - b * SPI;
        y[(long)(b * 256 + og2) * SPI + sp] =
            (unsigned short)f2bs(slab[lm * 17 + oc2]);
      }
    }
    __syncthreads();
  }
}

// ---------- filtered_lrelu v3: bf16 datapath, column strips ----------
// One block = (image, 16-out-col strip), 16384 blocks, 256 thr.
// All intermediates bf16 in LDS: b128 carries 8 values -> LDS wave-instrs
// halve vs f32 (R1 counters: kernel is LDS-pipe-bound), LDS 39->21.6KB ->
// 7 blocks/CU. bufY[66][32] (overlays t2), t1[138][32], t2[138][48],
// t3[64][48] (overlays t1). Strip covers out cols [c0,c0+15]; bufY cols
// c0-4..c0+21 in slots 0..25 (26..31 zero); t2/t3 local cols 0..41 used.
struct Filt { float f[12]; };

__global__ __launch_bounds__(256) void k_lrelu(
    const unsigned short* __restrict__ y, float* __restrict__ out, Filt ft) {
  __shared__ __align__(16) short t1s[138 * 32];   // 8832 B
  __shared__ __align__(16) short t2s[138 * 48];   // 13248 B
  short* bufYs = t2s;                             // [66][32]
  short* t3s = t1s;                               // [64][48]
  const int t = threadIdx.x;
  const int strip = blockIdx.x & 3;
  const long img = blockIdx.x >> 2;
  const int c0 = strip * 16;
  const unsigned short* ysrc = y + img * SPI;

  // phase 1: load bufY [66][32] bf16 (cols c0-4..c0+21 -> slots 0..25, rest 0)
  #pragma unroll
  for (int p = 0; p < 2; ++p) {
    int e = p * 256 + t;
    if (e < 264) {
      int r = e >> 2, cg = e & 3;
      int cbase = c0 - 4 + 8 * cg;
      if (cg < 3 && cbase >= 0 && cbase + 7 <= 65) {
        const unsigned int* src = (const unsigned int*)(ysrc + r * 66 + cbase);
        unsigned int u0 = src[0], u1 = src[1], u2 = src[2], u3 = src[3];
        uint4 pk = make_uint4(u0, u1, u2, u3);
        *(uint4*)(bufYs + r * 32 + 8 * cg) = pk;
      } else {
        bf16x8 pk;
        #pragma unroll
        for (int k = 0; k < 8; ++k) {
          int lc = 8 * cg + k, c = c0 - 4 + lc;
          pk[k] = (lc < 26 && c >= 0 && c < 66) ? (short)ysrc[r * 66 + c] : (short)0;
        }
        *(bf16x8*)(bufYs + r * 32 + 8 * cg) = pk;
      }
    }
  }
  __syncthreads();

  // phase 2: vertical up-FIR -> t1 [138][32] bf16, 8-col groups
  #pragma unroll
  for (int p = 0; p < 3; ++p) {
    int e = p * 256 + t;
    if (e < 552) {                        // 138 rows x 4 groups
      int rr = e >> 2, cg = e & 3;
      int p0 = (rr + 1) & 1;
      int yr0 = (rr + p0 - 9) >> 1;
      float a[8] = {0.f, 0.f, 0.f, 0.f, 0.f, 0.f, 0.f, 0.f};
      #pragma unroll
      for (int j = 0; j < 6; ++j) {
        int yr = yr0 + j;
        if (yr >= 0 && yr < 66) {
          float cf = ft.f[2 * j + p0];
          bf16x8 v = *(const bf16x8*)(bufYs + yr * 32 + 8 * cg);
          #pragma unroll
          for (int k = 0; k < 8; ++k) a[k] += cf * bf2f(v[k]);
        }
      }
      bf16x8 pk;
      #pragma unroll
      for (int k = 0; k < 8; ++k) pk[k] = f2bs(2.f * a[k]);
      *(bf16x8*)(t1s + rr * 32 + 8 * cg) = pk;
    }
  }
  __syncthreads();

  // phase 3: horizontal up-FIR + lrelu*sqrt2 + clamp -> t2 [138][48] bf16
  // u-quad g: outputs cols 8g..8g+7 from t1 cols 4g..4g+8 (12 loaded)
  #pragma unroll
  for (int p = 0; p < 4; ++p) {
    int e = p * 256 + t;
    if (e < 828) {                        // 138 rows x 6 groups
      int rr = e / 6, g = e - rr * 6;
      const short* tr = t1s + rr * 32 + 4 * g;
      float w[12];
      #pragma unroll
      for (int q = 0; q < 3; ++q) {
        short4v v = *(const short4v*)(tr + 4 * q);
        #pragma unroll
        for (int k = 0; k < 4; ++k) w[4 * q + k] = bf2f(v[k]);
      }
      bf16x8 pk;
      #pragma unroll
      for (int i = 0; i < 4; ++i) {
        float a0 = 0.f, a1 = 0.f;
        #pragma unroll
        for (int j = 0; j < 6; ++j) {
          float x = w[i + j];
          a0 += ft.f[2 * j + 1] * x;      // col 2u (odd taps)
          a1 += ft.f[2 * j] * x;          // col 2u+1 (even taps)
        }
        a0 *= 2.f; a1 *= 2.f;
        a0 = (a0 < 0.f ? 0.2f * a0 : a0) * 1.41421356237f;
        a1 = (a1 < 0.f ? 0.2f * a1 : a1) * 1.41421356237f;
        a0 = fminf(fmaxf(a0, -256.f), 256.f);
        a1 = fminf(fmaxf(a1, -256.f), 256.f);
        pk[2 * i] = f2bs(a0);
        pk[2 * i + 1] = f2bs(a1);
      }
      *(bf16x8*)(t2s + rr * 48 + 8 * g) = pk;
    }
  }
  __syncthreads();

  // phase 4: vertical down-FIR (stride 2) -> t3 [64][48] bf16, 8-col groups
  #pragma unroll
  for (int p = 0; p < 2; ++p) {
    int e = p * 256 + t;
    if (e < 384) {                        // 64 rows x 6 groups
      int pp = e / 6, cg = e - pp * 6;
      const short* col = t2s + (2 * pp) * 48 + 8 * cg;
      float a[8] = {0.f, 0.f, 0.f, 0.f, 0.f, 0.f, 0.f, 0.f};
      #pragma unroll
      for (int j = 0; j < 12; ++j) {
        float cf = ft.f[j];
        bf16x8 v = *(const bf16x8*)(col + j * 48);
        #pragma unroll
        for (int k = 0; k < 8; ++k) a[k] += cf * bf2f(v[k]);
      }
      bf16x8 pk;
      #pragma unroll
      for (int k = 0; k < 8; ++k) pk[k] = f2bs(a[k]);
      *(bf16x8*)(t3s + pp * 48 + 8 * cg) = pk;
    }
  }
  __syncthreads();

  // phase 5: horizontal down-FIR (stride 2) + store f32, 4 outs/thread
  {
    int pp = t >> 2, v = t & 3;           // 64 rows x 4 quads
    const short* row = t3s + pp * 48 + 8 * v;
    float w[20];
    #pragma unroll
    for (int q = 0; q < 5; ++q) {
      short4v x = *(const short4v*)(row + 4 * q);
      #pragma unroll
      for (int k = 0; k < 4; ++k) w[4 * q + k] = bf2f(x[k]);
    }
    float a0 = 0.f, a1 = 0.f, a2 = 0.f, a3 = 0.f;
    #pragma unroll
    for (int j = 0; j < 12; ++j) {
      float cf = ft.f[j];
      a0 += cf * w[j]; a1 += cf * w[j + 2]; a2 += cf * w[j + 4]; a3 += cf * w[j + 6];
    }
    *(float4*)&out[img * 4096 + pp * 64 + c0 + 4 * v] = make_float4(a0, a1, a2, a3);
  }
}

// ---------- host ----------
static double bessel_i0(double x) {
  double q = x * x * 0.25, term = 1.0, sum = 1.0;
  for (int k = 1; k < 64; ++k) {
    term *= q / ((double)k * (double)k);
    sum += term;
    if (term < sum * 1e-18) break;
  }
  return sum;
}

extern "C" void kernel_launch(void* const* d_in, const int* in_sizes, int n_in,
                              void* d_out, int out_size, void* d_ws, size_t ws_size,
                              hipStream_t stream) {
  const float* x   = (const float*)d_in[0];
  const float* w   = (const float*)d_in[1];
  const float* aw  = (const float*)d_in[2];
  const float* ab  = (const float*)d_in[3];
  const float* cw  = (const float*)d_in[4];
  const float* cb  = (const float*)d_in[5];
  const float* ema = (const float*)d_in[6];
  float* out = (float*)d_out;
  char* ws = (char*)d_ws;

  float* styles        = (float*)(ws + 0);          // 16 KB
  float* scal          = (float*)(ws + 16384);      // 16 B
  float* wsq           = (float*)(ws + 16640);      // 256 KB
  float* dco           = (float*)(ws + 278784);     // 16 KB
  __hip_bfloat16* wbt  = (__hip_bfloat16*)(ws + 295168);   // 1.18 MB  [9][256][256]
  unsigned short* xp   = (unsigned short*)(ws + 1474816);  // 37.9 MB  [16][68][68][256]
  unsigned short* y    = (unsigned short*)(ws + 39354624); // 35.7 MB  [16][256][66][66] bf16

  // firwin(12, 16, width=32, fs=128) with Kaiser window (double precision)
  Filt ft;
  {
    double atten = 2.285 * 11.0 * M_PI * 0.5 + 7.95;
    double beta;
    if (atten > 50.0) beta = 0.1102 * (atten - 8.7);
    else if (atten > 21.0) beta = 0.5842 * pow(atten - 21.0, 0.4) + 0.07886 * (atten - 21.0);
    else beta = 0.0;
    double i0b = bessel_i0(beta);
    double h[12], ssum = 0.0;
    for (int n = 0; n < 12; ++n) {
      double xx = ((double)n - 5.5) / 5.5;
      double win = bessel_i0(beta * sqrt(1.0 - xx * xx)) / i0b;
      double mm = ((double)n - 5.5) * 0.25;
      double snc = sin(M_PI * mm) / (M_PI * mm);
      h[n] = 0.25 * snc * win;
      ssum += h[n];
    }
    for (int n = 0; n < 12; ++n) ft.f[n] = (float)(h[n] / ssum);
  }

  k_styles <<<16, 256, 0, stream>>>(w, aw, ab, styles);
  k_scalars<<<1, 256, 0, stream>>>(styles, ema, scal);
  k_wnorm  <<<256, 256, 0, stream>>>(cw, wsq, wbt);
  k_dcoefs <<<16, 256, 0, stream>>>(styles, wsq, scal, dco);
  k_xpad   <<<dim3(4, 68, 16), 256, 0, stream>>>(x, styles, scal, xp);
  k_conv   <<<dim3(2, 545), 256, 0, stream>>>(xp, (const unsigned short*)wbt, dco, cb, y);
  k_lrelu  <<<16384, 256, 0, stream>>>(y, out, ft);
}

// Round 11
// 352.382 us; speedup vs baseline: 1.2748x; 1.0360x over previous
//
#include <hip/hip_runtime.h>
#include <hip/hip_bf16.h>
#include <math.h>

// StyleGAN3 SynthesisLayer forward, MI355X.
// B=16, CIN=COUT=256, H=W=64, K=3, up=2 down=2 taps=12, conv out 66x66,
// up-FIR out 138x138, final out 64x64.

typedef __attribute__((ext_vector_type(8))) short bf16x8;
typedef __attribute__((ext_vector_type(4))) short short4v;
typedef __attribute__((ext_vector_type(4))) float f32x4;

#define NM 69696         // 16*66*66 flattened conv-output positions
#define SPI 4356         // 66*66 spatial per image

__device__ inline void gload16(const void* g, void* l) {
  __builtin_amdgcn_global_load_lds((const __attribute__((address_space(1))) void*)g,
                                   (__attribute__((address_space(3))) void*)l, 16, 0, 0);
}
static __device__ __forceinline__ float bf2f(short h) {
  union { unsigned u; float f; } c;
  c.u = ((unsigned)(unsigned short)h) << 16;
  return c.f;
}
static __device__ __forceinline__ short f2bs(float f) {
  __hip_bfloat16 h = __float2bfloat16(f);
  return *(short*)&h;
}

// ---------- styles = w @ aw^T / sqrt(512) + ab ----------
__global__ __launch_bounds__(256) void k_styles(
    const float* __restrict__ w, const float* __restrict__ aw,
    const float* __restrict__ ab, float* __restrict__ styles) {
  __shared__ float lw[512];
  int b = blockIdx.x, t = threadIdx.x;
  lw[t] = w[b * 512 + t];
  lw[t + 256] = w[b * 512 + t + 256];
  __syncthreads();
  const float* row = aw + (long)t * 512;
  float acc = 0.f;
  #pragma unroll 4
  for (int d = 0; d < 512; ++d) acc += row[d] * lw[d];
  styles[b * 256 + t] = acc * 0.04419417382415922f + ab[t];
}

// ---------- scal[0] = 1/mean(styles^2), scal[1] = rsqrt(ema) ----------
__global__ __launch_bounds__(256) void k_scalars(
    const float* __restrict__ styles, const float* __restrict__ ema,
    float* __restrict__ scal) {
  __shared__ float red[256];
  int t = threadIdx.x;
  float s = 0.f;
  #pragma unroll
  for (int k = 0; k < 16; ++k) { float v = styles[t + k * 256]; s += v * v; }
  red[t] = s; __syncthreads();
  for (int off = 128; off > 0; off >>= 1) {
    if (t < off) red[t] += red[t + off];
    __syncthreads();
  }
  if (t == 0) { scal[0] = 4096.0f / red[0]; scal[1] = 1.0f / sqrtf(ema[0]); }
}

// ---------- per-o weight norm; wsq[o][i]; wbt[tap][o][i] bf16 (R1 layout) ----------
__global__ __launch_bounds__(256) void k_wnorm(
    const float* __restrict__ cw, float* __restrict__ wsq,
    __hip_bfloat16* __restrict__ wbt) {
  __shared__ float red[256];
  __shared__ float lws, lws2;
  int o = blockIdx.x, t = threadIdx.x;
  const float* base = cw + o * 2304;
  float s = 0.f;
  #pragma unroll
  for (int k = 0; k < 9; ++k) { float v = base[t + k * 256]; s += v * v; }
  red[t] = s; __syncthreads();
  for (int off = 128; off > 0; off >>= 1) {
    if (t < off) red[t] += red[t + off];
    __syncthreads();
  }
  if (t == 0) { lws2 = 2304.0f / red[0]; lws = sqrtf(lws2); }
  __syncthreads();
  const float* r9 = base + t * 9;
  float s9 = 0.f;
  #pragma unroll
  for (int k = 0; k < 9; ++k) s9 += r9[k] * r9[k];
  wsq[o * 256 + t] = lws2 * s9;
  #pragma unroll
  for (int tap = 0; tap < 9; ++tap)
    wbt[(tap * 256 + o) * 256 + t] = __float2bfloat16(r9[tap] * lws);
}

// ---------- dcoefs[b][o] = rsqrt(sum_i s^2 * wsq + 1e-8) * input_gain ----------
__global__ __launch_bounds__(256) void k_dcoefs(
    const float* __restrict__ styles, const float* __restrict__ wsq,
    const float* __restrict__ scal, float* __restrict__ dco) {
  __shared__ float sn2[256];
  int b = blockIdx.x, t = threadIdx.x;
  float v = styles[b * 256 + t];
  sn2[t] = v * v * scal[0];
  __syncthreads();
  const float* wr = wsq + t * 256;
  float acc = 0.f;
  #pragma unroll 4
  for (int i = 0; i < 256; ++i) acc += sn2[i] * wr[i];
  dco[b * 256 + t] = (1.0f / sqrtf(acc + 1e-8f)) * scal[1];
}

// ---------- xs_pad[b][68][68][256] bf16, NHWC, style-scaled (R1 layout) ----------
__global__ __launch_bounds__(256) void k_xpad(
    const float* __restrict__ x, const float* __restrict__ styles,
    const float* __restrict__ scal, unsigned short* __restrict__ xp) {
  __shared__ float lx[64 * 65];
  __shared__ float sc[64];
  int ig = blockIdx.x, hp = blockIdx.y, b = blockIdx.z, t = threadIdx.x;
  int i0 = ig * 64;
  float ss = sqrtf(scal[0]);
  if (t < 64) sc[t] = styles[b * 256 + i0 + t] * ss;
  int h = hp - 2;
  bool inh = (hp >= 2) && (hp < 66);
  if (inh) {
    #pragma unroll
    for (int p = 0; p < 16; ++p) {
      int idx = p * 256 + t; int i = idx >> 6, w = idx & 63;
      lx[i * 65 + w] = x[((b * 256 + i0 + i) * 64 + h) * 64 + w];
    }
  }
  __syncthreads();
  unsigned short* dst = xp + ((long)(b * 68 + hp) * 68) * 256 + i0;
  #pragma unroll
  for (int p = 0; p < 17; ++p) {
    int idx = p * 256 + t; int wp = idx >> 6, i = idx & 63;
    float v = 0.f;
    if (inh && wp >= 2 && wp < 66) v = lx[i * 65 + (wp - 2)] * sc[i];
    __hip_bfloat16 bv = __float2bfloat16(v);
    dst[wp * 256 + i] = *(unsigned short*)&bv;
  }
}

// ---------- conv: R1-proven implicit GEMM + bijective XCD swizzle ----------
// ONLY change vs R9: 1D grid 1090 with m204 bijective XCD swizzle so the two
// o-halves of each m-tile and m-neighbors (shared A rows/halo) land on the
// same XCD's L2 (R2 evidence: FETCH 188->33 MB with this mapping). Tile,
// schedule, swizzle, epilogue all unchanged (proven 197us / absmax 0.0078).
__global__ __launch_bounds__(256) void k_conv(
    const unsigned short* __restrict__ xp, const unsigned short* __restrict__ wbt,
    const float* __restrict__ dco, const float* __restrict__ bias,
    unsigned short* __restrict__ y) {
  __shared__ __align__(16) unsigned short As[128 * 64];
  __shared__ __align__(16) unsigned short Bs[128 * 64];
  const int t = threadIdx.x;
  const int lane = t & 63;
  const int wave = t >> 6;
  const int wm = wave >> 1, wn = wave & 1;

  // bijective XCD swizzle: nwg=1090 = 8*136 + 2 (xcd 0,1 get 137)
  const int f = blockIdx.x;
  const int xcd = f & 7, pos = f >> 3;
  const int wgid = (xcd < 2 ? xcd * 137 : 274 + (xcd - 2) * 136) + pos;
  const int o0 = (wgid & 1) * 128;
  const int m0 = (wgid >> 1) * 128;

  int abase[4], bbase[4];
  #pragma unroll
  for (int j = 0; j < 4; ++j) {
    int task = j * 256 + t;
    int lm = task >> 3, ch = task & 7;
    int csrc = ch ^ (lm & 7);
    int m = m0 + lm; if (m > NM - 1) m = NM - 1;
    int b = m / SPI; int sp = m - b * SPI;
    int r = sp / 66; int c = sp - r * 66;
    abase[j] = (((b * 68 + r) * 68 + c) << 9) + (csrc << 4);   // bytes
    bbase[j] = ((o0 + lm) << 9) + (csrc << 4);                 // bytes
  }
  f32x4 acc[4][4] = {};
  const char* xb = (const char*)xp;
  const char* wb = (const char*)wbt;
  char* asb = (char*)As;
  char* bsb = (char*)Bs;

  for (int kk = 0; kk < 36; ++kk) {
    int tap = kk >> 2;
    int ch0b = (kk & 3) << 7;            // ch0 * 2 bytes
    int ky = tap / 3, kx = tap - ky * 3;
    int aoff = ((ky * 68 + kx) << 9) + ch0b;
    int boff = (tap << 17) + ch0b;
    #pragma unroll
    for (int j = 0; j < 4; ++j) {
      gload16(xb + abase[j] + aoff, asb + ((j * 256 + t) << 4));
      gload16(wb + bbase[j] + boff, bsb + ((j * 256 + t) << 4));
    }
    __syncthreads();   // drains vmcnt -> tiles visible
    #pragma unroll
    for (int h = 0; h < 2; ++h) {
      bf16x8 av[4], bv[4];
      #pragma unroll
      for (int fm = 0; fm < 4; ++fm) {
        int arow = wm * 64 + fm * 16 + (lane & 15);
        int chk = ((h << 2) + (lane >> 4)) ^ (arow & 7);
        av[fm] = *(const bf16x8*)(asb + arow * 128 + chk * 16);
      }
      #pragma unroll
      for (int fn = 0; fn < 4; ++fn) {
        int brow = wn * 64 + fn * 16 + (lane & 15);
        int chk = ((h << 2) + (lane >> 4)) ^ (brow & 7);
        bv[fn] = *(const bf16x8*)(bsb + brow * 128 + chk * 16);
      }
      #pragma unroll
      for (int fm = 0; fm < 4; ++fm)
        #pragma unroll
        for (int fn = 0; fn < 4; ++fn)
          acc[fm][fn] = __builtin_amdgcn_mfma_f32_16x16x32_bf16(
              av[fm], bv[fn], acc[fm][fn], 0, 0, 0);
    }
    __syncthreads();   // readers done before next overwrite
  }

  // Epilogue: scale + bias, transpose via LDS slab [128m][17], write NCHW bf16.
  float* slab = (float*)As;
  #pragma unroll
  for (int s = 0; s < 8; ++s) {
    if (wn == (s >> 2)) {
      const int sfn = s & 3;
      int ocol = lane & 15;
      int og = o0 + s * 16 + ocol;
      float bo = bias[og];
      #pragma unroll
      for (int fm = 0; fm < 4; ++fm) {
        #pragma unroll
        for (int j = 0; j < 4; ++j) {
          int lm = wm * 64 + fm * 16 + ((lane >> 4) << 2) + j;
          int m = m0 + lm;
          float v = acc[fm][sfn][j];
          if (m < NM) {
            int b = m / SPI;
            v = v * dco[b * 256 + og] + bo;
          }
          slab[lm * 17 + ocol] = v;
        }
      }
    }
    __syncthreads();
    int oc2 = t >> 4;
    int og2 = o0 + s * 16 + oc2;
    #pragma unroll
    for (int p = 0; p < 8; ++p) {
      int lm = (t & 15) + p * 16;
      int m = m0 + lm;
      if (m < NM) {
        int b = m / SPI; int sp = m - b * SPI;
        y[(long)(b * 256 + og2) * SPI + sp] =
            (unsigned short)f2bs(slab[lm * 17 + oc2]);
      }
    }
    __syncthreads();
  }
}

// ---------- filtered_lrelu v3: bf16 datapath, column strips (R9, unchanged) ----------
struct Filt { float f[12]; };

__global__ __launch_bounds__(256) void k_lrelu(
    const unsigned short* __restrict__ y, float* __restrict__ out, Filt ft) {
  __shared__ __align__(16) short t1s[138 * 32];   // 8832 B
  __shared__ __align__(16) short t2s[138 * 48];   // 13248 B
  short* bufYs = t2s;                             // [66][32]
  short* t3s = t1s;                               // [64][48]
  const int t = threadIdx.x;
  const int strip = blockIdx.x & 3;
  const long img = blockIdx.x >> 2;
  const int c0 = strip * 16;
  const unsigned short* ysrc = y + img * SPI;

  // phase 1: load bufY [66][32] bf16 (cols c0-4..c0+21 -> slots 0..25, rest 0)
  #pragma unroll
  for (int p = 0; p < 2; ++p) {
    int e = p * 256 + t;
    if (e < 264) {
      int r = e >> 2, cg = e & 3;
      int cbase = c0 - 4 + 8 * cg;
      if (cg < 3 && cbase >= 0 && cbase + 7 <= 65) {
        const unsigned int* src = (const unsigned int*)(ysrc + r * 66 + cbase);
        unsigned int u0 = src[0], u1 = src[1], u2 = src[2], u3 = src[3];
        uint4 pk = make_uint4(u0, u1, u2, u3);
        *(uint4*)(bufYs + r * 32 + 8 * cg) = pk;
      } else {
        bf16x8 pk;
        #pragma unroll
        for (int k = 0; k < 8; ++k) {
          int lc = 8 * cg + k, c = c0 - 4 + lc;
          pk[k] = (lc < 26 && c >= 0 && c < 66) ? (short)ysrc[r * 66 + c] : (short)0;
        }
        *(bf16x8*)(bufYs + r * 32 + 8 * cg) = pk;
      }
    }
  }
  __syncthreads();

  // phase 2: vertical up-FIR -> t1 [138][32] bf16, 8-col groups
  #pragma unroll
  for (int p = 0; p < 3; ++p) {
    int e = p * 256 + t;
    if (e < 552) {                        // 138 rows x 4 groups
      int rr = e >> 2, cg = e & 3;
      int p0 = (rr + 1) & 1;
      int yr0 = (rr + p0 - 9) >> 1;
      float a[8] = {0.f, 0.f, 0.f, 0.f, 0.f, 0.f, 0.f, 0.f};
      #pragma unroll
      for (int j = 0; j < 6; ++j) {
        int yr = yr0 + j;
        if (yr >= 0 && yr < 66) {
          float cf = ft.f[2 * j + p0];
          bf16x8 v = *(const bf16x8*)(bufYs + yr * 32 + 8 * cg);
          #pragma unroll
          for (int k = 0; k < 8; ++k) a[k] += cf * bf2f(v[k]);
        }
      }
      bf16x8 pk;
      #pragma unroll
      for (int k = 0; k < 8; ++k) pk[k] = f2bs(2.f * a[k]);
      *(bf16x8*)(t1s + rr * 32 + 8 * cg) = pk;
    }
  }
  __syncthreads();

  // phase 3: horizontal up-FIR + lrelu*sqrt2 + clamp -> t2 [138][48] bf16
  #pragma unroll
  for (int p = 0; p < 4; ++p) {
    int e = p * 256 + t;
    if (e < 828) {                        // 138 rows x 6 groups
      int rr = e / 6, g = e - rr * 6;
      const short* tr = t1s + rr * 32 + 4 * g;
      float w[12];
      #pragma unroll
      for (int q = 0; q < 3; ++q) {
        short4v v = *(const short4v*)(tr + 4 * q);
        #pragma unroll
        for (int k = 0; k < 4; ++k) w[4 * q + k] = bf2f(v[k]);
      }
      bf16x8 pk;
      #pragma unroll
      for (int i = 0; i < 4; ++i) {
        float a0 = 0.f, a1 = 0.f;
        #pragma unroll
        for (int j = 0; j < 6; ++j) {
          float x = w[i + j];
          a0 += ft.f[2 * j + 1] * x;      // col 2u (odd taps)
          a1 += ft.f[2 * j] * x;          // col 2u+1 (even taps)
        }
        a0 *= 2.f; a1 *= 2.f;
        a0 = (a0 < 0.f ? 0.2f * a0 : a0) * 1.41421356237f;
        a1 = (a1 < 0.f ? 0.2f * a1 : a1) * 1.41421356237f;
        a0 = fminf(fmaxf(a0, -256.f), 256.f);
        a1 = fminf(fmaxf(a1, -256.f), 256.f);
        pk[2 * i] = f2bs(a0);
        pk[2 * i + 1] = f2bs(a1);
      }
      *(bf16x8*)(t2s + rr * 48 + 8 * g) = pk;
    }
  }
  __syncthreads();

  // phase 4: vertical down-FIR (stride 2) -> t3 [64][48] bf16, 8-col groups
  #pragma unroll
  for (int p = 0; p < 2; ++p) {
    int e = p * 256 + t;
    if (e < 384) {                        // 64 rows x 6 groups
      int pp = e / 6, cg = e - pp * 6;
      const short* col = t2s + (2 * pp) * 48 + 8 * cg;
      float a[8] = {0.f, 0.f, 0.f, 0.f, 0.f, 0.f, 0.f, 0.f};
      #pragma unroll
      for (int j = 0; j < 12; ++j) {
        float cf = ft.f[j];
        bf16x8 v = *(const bf16x8*)(col + j * 48);
        #pragma unroll
        for (int k = 0; k < 8; ++k) a[k] += cf * bf2f(v[k]);
      }
      bf16x8 pk;
      #pragma unroll
      for (int k = 0; k < 8; ++k) pk[k] = f2bs(a[k]);
      *(bf16x8*)(t3s + pp * 48 + 8 * cg) = pk;
    }
  }
  __syncthreads();

  // phase 5: horizontal down-FIR (stride 2) + store f32, 4 outs/thread
  {
    int pp = t >> 2, v = t & 3;           // 64 rows x 4 quads
    const short* row = t3s + pp * 48 + 8 * v;
    float w[20];
    #pragma unroll
    for (int q = 0; q < 5; ++q) {
      short4v x = *(const short4v*)(row + 4 * q);
      #pragma unroll
      for (int k = 0; k < 4; ++k) w[4 * q + k] = bf2f(x[k]);
    }
    float a0 = 0.f, a1 = 0.f, a2 = 0.f, a3 = 0.f;
    #pragma unroll
    for (int j = 0; j < 12; ++j) {
      float cf = ft.f[j];
      a0 += cf * w[j]; a1 += cf * w[j + 2]; a2 += cf * w[j + 4]; a3 += cf * w[j + 6];
    }
    *(float4*)&out[img * 4096 + pp * 64 + c0 + 4 * v] = make_float4(a0, a1, a2, a3);
  }
}

// ---------- host ----------
static double bessel_i0(double x) {
  double q = x * x * 0.25, term = 1.0, sum = 1.0;
  for (int k = 1; k < 64; ++k) {
    term *= q / ((double)k * (double)k);
    sum += term;
    if (term < sum * 1e-18) break;
  }
  return sum;
}

extern "C" void kernel_launch(void* const* d_in, const int* in_sizes, int n_in,
                              void* d_out, int out_size, void* d_ws, size_t ws_size,
                              hipStream_t stream) {
  const float* x   = (const float*)d_in[0];
  const float* w   = (const float*)d_in[1];
  const float* aw  = (const float*)d_in[2];
  const float* ab  = (const float*)d_in[3];
  const float* cw  = (const float*)d_in[4];
  const float* cb  = (const float*)d_in[5];
  const float* ema = (const float*)d_in[6];
  float* out = (float*)d_out;
  char* ws = (char*)d_ws;

  float* styles        = (float*)(ws + 0);          // 16 KB
  float* scal          = (float*)(ws + 16384);      // 16 B
  float* wsq           = (float*)(ws + 16640);      // 256 KB
  float* dco           = (float*)(ws + 278784);     // 16 KB
  __hip_bfloat16* wbt  = (__hip_bfloat16*)(ws + 295168);   // 1.18 MB  [9][256][256]
  unsigned short* xp   = (unsigned short*)(ws + 1474816);  // 37.9 MB  [16][68][68][256]
  unsigned short* y    = (unsigned short*)(ws + 39354624); // 35.7 MB  [16][256][66][66] bf16

  // firwin(12, 16, width=32, fs=128) with Kaiser window (double precision)
  Filt ft;
  {
    double atten = 2.285 * 11.0 * M_PI * 0.5 + 7.95;
    double beta;
    if (atten > 50.0) beta = 0.1102 * (atten - 8.7);
    else if (atten > 21.0) beta = 0.5842 * pow(atten - 21.0, 0.4) + 0.07886 * (atten - 21.0);
    else beta = 0.0;
    double i0b = bessel_i0(beta);
    double h[12], ssum = 0.0;
    for (int n = 0; n < 12; ++n) {
      double xx = ((double)n - 5.5) / 5.5;
      double win = bessel_i0(beta * sqrt(1.0 - xx * xx)) / i0b;
      double mm = ((double)n - 5.5) * 0.25;
      double snc = sin(M_PI * mm) / (M_PI * mm);
      h[n] = 0.25 * snc * win;
      ssum += h[n];
    }
    for (int n = 0; n < 12; ++n) ft.f[n] = (float)(h[n] / ssum);
  }

  k_styles <<<16, 256, 0, stream>>>(w, aw, ab, styles);
  k_scalars<<<1, 256, 0, stream>>>(styles, ema, scal);
  k_wnorm  <<<256, 256, 0, stream>>>(cw, wsq, wbt);
  k_dcoefs <<<16, 256, 0, stream>>>(styles, wsq, scal, dco);
  k_xpad   <<<dim3(4, 68, 16), 256, 0, stream>>>(x, styles, scal, xp);
  k_conv   <<<1090, 256, 0, stream>>>(xp, (const unsigned short*)wbt, dco, cb, y);
  k_lrelu  <<<16384, 256, 0, stream>>>(y, out, ft);
}

// Round 12
// 321.971 us; speedup vs baseline: 1.3952x; 1.0945x over previous
//
#include <hip/hip_runtime.h>
#include <hip/hip_bf16.h>
#include <math.h>

// StyleGAN3 SynthesisLayer forward, MI355X.
// B=16, CIN=COUT=256, H=W=64, K=3, up=2 down=2 taps=12, conv out 66x66,
// up-FIR out 138x138, final out 64x64.

typedef __attribute__((ext_vector_type(8))) short bf16x8;
typedef __attribute__((ext_vector_type(4))) short short4v;
typedef __attribute__((ext_vector_type(4))) float f32x4;

#define NM 69696         // 16*66*66 flattened conv-output positions
#define SPI 4356         // 66*66 spatial per image

__device__ inline void gload16(const void* g, void* l) {
  __builtin_amdgcn_global_load_lds((const __attribute__((address_space(1))) void*)g,
                                   (__attribute__((address_space(3))) void*)l, 16, 0, 0);
}
static __device__ __forceinline__ float bf2f(short h) {
  union { unsigned u; float f; } c;
  c.u = ((unsigned)(unsigned short)h) << 16;
  return c.f;
}
static __device__ __forceinline__ short f2bs(float f) {
  __hip_bfloat16 h = __float2bfloat16(f);
  return *(short*)&h;
}

// ---------- styles = w @ aw^T / sqrt(512) + ab ----------
__global__ __launch_bounds__(256) void k_styles(
    const float* __restrict__ w, const float* __restrict__ aw,
    const float* __restrict__ ab, float* __restrict__ styles) {
  __shared__ float lw[512];
  int b = blockIdx.x, t = threadIdx.x;
  lw[t] = w[b * 512 + t];
  lw[t + 256] = w[b * 512 + t + 256];
  __syncthreads();
  const float* row = aw + (long)t * 512;
  float acc = 0.f;
  #pragma unroll 4
  for (int d = 0; d < 512; ++d) acc += row[d] * lw[d];
  styles[b * 256 + t] = acc * 0.04419417382415922f + ab[t];
}

// ---------- scal[0] = 1/mean(styles^2), scal[1] = rsqrt(ema) ----------
__global__ __launch_bounds__(256) void k_scalars(
    const float* __restrict__ styles, const float* __restrict__ ema,
    float* __restrict__ scal) {
  __shared__ float red[256];
  int t = threadIdx.x;
  float s = 0.f;
  #pragma unroll
  for (int k = 0; k < 16; ++k) { float v = styles[t + k * 256]; s += v * v; }
  red[t] = s; __syncthreads();
  for (int off = 128; off > 0; off >>= 1) {
    if (t < off) red[t] += red[t + off];
    __syncthreads();
  }
  if (t == 0) { scal[0] = 4096.0f / red[0]; scal[1] = 1.0f / sqrtf(ema[0]); }
}

// ---------- per-o weight norm; wsq[o][i]; wbt[tap][o][i] bf16 (R1 layout) ----------
__global__ __launch_bounds__(256) void k_wnorm(
    const float* __restrict__ cw, float* __restrict__ wsq,
    __hip_bfloat16* __restrict__ wbt) {
  __shared__ float red[256];
  __shared__ float lws, lws2;
  int o = blockIdx.x, t = threadIdx.x;
  const float* base = cw + o * 2304;
  float s = 0.f;
  #pragma unroll
  for (int k = 0; k < 9; ++k) { float v = base[t + k * 256]; s += v * v; }
  red[t] = s; __syncthreads();
  for (int off = 128; off > 0; off >>= 1) {
    if (t < off) red[t] += red[t + off];
    __syncthreads();
  }
  if (t == 0) { lws2 = 2304.0f / red[0]; lws = sqrtf(lws2); }
  __syncthreads();
  const float* r9 = base + t * 9;
  float s9 = 0.f;
  #pragma unroll
  for (int k = 0; k < 9; ++k) s9 += r9[k] * r9[k];
  wsq[o * 256 + t] = lws2 * s9;
  #pragma unroll
  for (int tap = 0; tap < 9; ++tap)
    wbt[(tap * 256 + o) * 256 + t] = __float2bfloat16(r9[tap] * lws);
}

// ---------- dcoefs[b][o] = rsqrt(sum_i s^2 * wsq + 1e-8) * input_gain ----------
__global__ __launch_bounds__(256) void k_dcoefs(
    const float* __restrict__ styles, const float* __restrict__ wsq,
    const float* __restrict__ scal, float* __restrict__ dco) {
  __shared__ float sn2[256];
  int b = blockIdx.x, t = threadIdx.x;
  float v = styles[b * 256 + t];
  sn2[t] = v * v * scal[0];
  __syncthreads();
  const float* wr = wsq + t * 256;
  float acc = 0.f;
  #pragma unroll 4
  for (int i = 0; i < 256; ++i) acc += sn2[i] * wr[i];
  dco[b * 256 + t] = (1.0f / sqrtf(acc + 1e-8f)) * scal[1];
}

// ---------- xs_pad[b][68][68][256] bf16, NHWC, style-scaled (R1 layout) ----------
__global__ __launch_bounds__(256) void k_xpad(
    const float* __restrict__ x, const float* __restrict__ styles,
    const float* __restrict__ scal, unsigned short* __restrict__ xp) {
  __shared__ float lx[64 * 65];
  __shared__ float sc[64];
  int ig = blockIdx.x, hp = blockIdx.y, b = blockIdx.z, t = threadIdx.x;
  int i0 = ig * 64;
  float ss = sqrtf(scal[0]);
  if (t < 64) sc[t] = styles[b * 256 + i0 + t] * ss;
  int h = hp - 2;
  bool inh = (hp >= 2) && (hp < 66);
  if (inh) {
    #pragma unroll
    for (int p = 0; p < 16; ++p) {
      int idx = p * 256 + t; int i = idx >> 6, w = idx & 63;
      lx[i * 65 + w] = x[((b * 256 + i0 + i) * 64 + h) * 64 + w];
    }
  }
  __syncthreads();
  unsigned short* dst = xp + ((long)(b * 68 + hp) * 68) * 256 + i0;
  #pragma unroll
  for (int p = 0; p < 17; ++p) {
    int idx = p * 256 + t; int wp = idx >> 6, i = idx & 63;
    float v = 0.f;
    if (inh && wp >= 2 && wp < 66) v = lx[i * 65 + (wp - 2)] * sc[i];
    __hip_bfloat16 bv = __float2bfloat16(v);
    dst[wp * 256 + i] = *(unsigned short*)&bv;
  }
}

// ---------- conv: R1 GEMM + XCD swizzle + OCCUPANCY FORCE ----------
// ONLY change vs R10: __launch_bounds__(256, 4). R10 diagnosis: VGPR 92 +
// AGPR 64 (acc) = 156 regs/thread > 128 -> 2 waves/SIMD = 2 blocks/CU
// (Occupancy 16.5%); all schedule variants plateaued because resident-wave
// count never changed. Forcing 4 waves/EU makes the allocator fit V+A <= 128
// (VGPR <= 64: rematerialize staging addresses; VALUBusy 28% has headroom).
// Watch: VGPR_Count ~64, scratch spills (would show as regression).
__global__ __launch_bounds__(256, 4) void k_conv(
    const unsigned short* __restrict__ xp, const unsigned short* __restrict__ wbt,
    const float* __restrict__ dco, const float* __restrict__ bias,
    unsigned short* __restrict__ y) {
  __shared__ __align__(16) unsigned short As[128 * 64];
  __shared__ __align__(16) unsigned short Bs[128 * 64];
  const int t = threadIdx.x;
  const int lane = t & 63;
  const int wave = t >> 6;
  const int wm = wave >> 1, wn = wave & 1;

  // bijective XCD swizzle: nwg=1090 = 8*136 + 2 (xcd 0,1 get 137)
  const int f = blockIdx.x;
  const int xcd = f & 7, pos = f >> 3;
  const int wgid = (xcd < 2 ? xcd * 137 : 274 + (xcd - 2) * 136) + pos;
  const int o0 = (wgid & 1) * 128;
  const int m0 = (wgid >> 1) * 128;

  int abase[4], bbase[4];
  #pragma unroll
  for (int j = 0; j < 4; ++j) {
    int task = j * 256 + t;
    int lm = task >> 3, ch = task & 7;
    int csrc = ch ^ (lm & 7);
    int m = m0 + lm; if (m > NM - 1) m = NM - 1;
    int b = m / SPI; int sp = m - b * SPI;
    int r = sp / 66; int c = sp - r * 66;
    abase[j] = (((b * 68 + r) * 68 + c) << 9) + (csrc << 4);   // bytes
    bbase[j] = ((o0 + lm) << 9) + (csrc << 4);                 // bytes
  }
  f32x4 acc[4][4] = {};
  const char* xb = (const char*)xp;
  const char* wb = (const char*)wbt;
  char* asb = (char*)As;
  char* bsb = (char*)Bs;

  for (int kk = 0; kk < 36; ++kk) {
    int tap = kk >> 2;
    int ch0b = (kk & 3) << 7;            // ch0 * 2 bytes
    int ky = tap / 3, kx = tap - ky * 3;
    int aoff = ((ky * 68 + kx) << 9) + ch0b;
    int boff = (tap << 17) + ch0b;
    #pragma unroll
    for (int j = 0; j < 4; ++j) {
      gload16(xb + abase[j] + aoff, asb + ((j * 256 + t) << 4));
      gload16(wb + bbase[j] + boff, bsb + ((j * 256 + t) << 4));
    }
    __syncthreads();   // drains vmcnt -> tiles visible
    #pragma unroll
    for (int h = 0; h < 2; ++h) {
      bf16x8 av[4], bv[4];
      #pragma unroll
      for (int fm = 0; fm < 4; ++fm) {
        int arow = wm * 64 + fm * 16 + (lane & 15);
        int chk = ((h << 2) + (lane >> 4)) ^ (arow & 7);
        av[fm] = *(const bf16x8*)(asb + arow * 128 + chk * 16);
      }
      #pragma unroll
      for (int fn = 0; fn < 4; ++fn) {
        int brow = wn * 64 + fn * 16 + (lane & 15);
        int chk = ((h << 2) + (lane >> 4)) ^ (brow & 7);
        bv[fn] = *(const bf16x8*)(bsb + brow * 128 + chk * 16);
      }
      #pragma unroll
      for (int fm = 0; fm < 4; ++fm)
        #pragma unroll
        for (int fn = 0; fn < 4; ++fn)
          acc[fm][fn] = __builtin_amdgcn_mfma_f32_16x16x32_bf16(
              av[fm], bv[fn], acc[fm][fn], 0, 0, 0);
    }
    __syncthreads();   // readers done before next overwrite
  }

  // Epilogue: scale + bias, transpose via LDS slab [128m][17], write NCHW bf16.
  float* slab = (float*)As;
  #pragma unroll
  for (int s = 0; s < 8; ++s) {
    if (wn == (s >> 2)) {
      const int sfn = s & 3;
      int ocol = lane & 15;
      int og = o0 + s * 16 + ocol;
      float bo = bias[og];
      #pragma unroll
      for (int fm = 0; fm < 4; ++fm) {
        #pragma unroll
        for (int j = 0; j < 4; ++j) {
          int lm = wm * 64 + fm * 16 + ((lane >> 4) << 2) + j;
          int m = m0 + lm;
          float v = acc[fm][sfn][j];
          if (m < NM) {
            int b = m / SPI;
            v = v * dco[b * 256 + og] + bo;
          }
          slab[lm * 17 + ocol] = v;
        }
      }
    }
    __syncthreads();
    int oc2 = t >> 4;
    int og2 = o0 + s * 16 + oc2;
    #pragma unroll
    for (int p = 0; p < 8; ++p) {
      int lm = (t & 15) + p * 16;
      int m = m0 + lm;
      if (m < NM) {
        int b = m / SPI; int sp = m - b * SPI;
        y[(long)(b * 256 + og2) * SPI + sp] =
            (unsigned short)f2bs(slab[lm * 17 + oc2]);
      }
    }
    __syncthreads();
  }
}

// ---------- filtered_lrelu v3: bf16 datapath, column strips (unchanged) ----------
struct Filt { float f[12]; };

__global__ __launch_bounds__(256) void k_lrelu(
    const unsigned short* __restrict__ y, float* __restrict__ out, Filt ft) {
  __shared__ __align__(16) short t1s[138 * 32];   // 8832 B
  __shared__ __align__(16) short t2s[138 * 48];   // 13248 B
  short* bufYs = t2s;                             // [66][32]
  short* t3s = t1s;                               // [64][48]
  const int t = threadIdx.x;
  const int strip = blockIdx.x & 3;
  const long img = blockIdx.x >> 2;
  const int c0 = strip * 16;
  const unsigned short* ysrc = y + img * SPI;

  // phase 1: load bufY [66][32] bf16 (cols c0-4..c0+21 -> slots 0..25, rest 0)
  #pragma unroll
  for (int p = 0; p < 2; ++p) {
    int e = p * 256 + t;
    if (e < 264) {
      int r = e >> 2, cg = e & 3;
      int cbase = c0 - 4 + 8 * cg;
      if (cg < 3 && cbase >= 0 && cbase + 7 <= 65) {
        const unsigned int* src = (const unsigned int*)(ysrc + r * 66 + cbase);
        unsigned int u0 = src[0], u1 = src[1], u2 = src[2], u3 = src[3];
        uint4 pk = make_uint4(u0, u1, u2, u3);
        *(uint4*)(bufYs + r * 32 + 8 * cg) = pk;
      } else {
        bf16x8 pk;
        #pragma unroll
        for (int k = 0; k < 8; ++k) {
          int lc = 8 * cg + k, c = c0 - 4 + lc;
          pk[k] = (lc < 26 && c >= 0 && c < 66) ? (short)ysrc[r * 66 + c] : (short)0;
        }
        *(bf16x8*)(bufYs + r * 32 + 8 * cg) = pk;
      }
    }
  }
  __syncthreads();

  // phase 2: vertical up-FIR -> t1 [138][32] bf16, 8-col groups
  #pragma unroll
  for (int p = 0; p < 3; ++p) {
    int e = p * 256 + t;
    if (e < 552) {                        // 138 rows x 4 groups
      int rr = e >> 2, cg = e & 3;
      int p0 = (rr + 1) & 1;
      int yr0 = (rr + p0 - 9) >> 1;
      float a[8] = {0.f, 0.f, 0.f, 0.f, 0.f, 0.f, 0.f, 0.f};
      #pragma unroll
      for (int j = 0; j < 6; ++j) {
        int yr = yr0 + j;
        if (yr >= 0 && yr < 66) {
          float cf = ft.f[2 * j + p0];
          bf16x8 v = *(const bf16x8*)(bufYs + yr * 32 + 8 * cg);
          #pragma unroll
          for (int k = 0; k < 8; ++k) a[k] += cf * bf2f(v[k]);
        }
      }
      bf16x8 pk;
      #pragma unroll
      for (int k = 0; k < 8; ++k) pk[k] = f2bs(2.f * a[k]);
      *(bf16x8*)(t1s + rr * 32 + 8 * cg) = pk;
    }
  }
  __syncthreads();

  // phase 3: horizontal up-FIR + lrelu*sqrt2 + clamp -> t2 [138][48] bf16
  #pragma unroll
  for (int p = 0; p < 4; ++p) {
    int e = p * 256 + t;
    if (e < 828) {                        // 138 rows x 6 groups
      int rr = e / 6, g = e - rr * 6;
      const short* tr = t1s + rr * 32 + 4 * g;
      float w[12];
      #pragma unroll
      for (int q = 0; q < 3; ++q) {
        short4v v = *(const short4v*)(tr + 4 * q);
        #pragma unroll
        for (int k = 0; k < 4; ++k) w[4 * q + k] = bf2f(v[k]);
      }
      bf16x8 pk;
      #pragma unroll
      for (int i = 0; i < 4; ++i) {
        float a0 = 0.f, a1 = 0.f;
        #pragma unroll
        for (int j = 0; j < 6; ++j) {
          float x = w[i + j];
          a0 += ft.f[2 * j + 1] * x;      // col 2u (odd taps)
          a1 += ft.f[2 * j] * x;          // col 2u+1 (even taps)
        }
        a0 *= 2.f; a1 *= 2.f;
        a0 = (a0 < 0.f ? 0.2f * a0 : a0) * 1.41421356237f;
        a1 = (a1 < 0.f ? 0.2f * a1 : a1) * 1.41421356237f;
        a0 = fminf(fmaxf(a0, -256.f), 256.f);
        a1 = fminf(fmaxf(a1, -256.f), 256.f);
        pk[2 * i] = f2bs(a0);
        pk[2 * i + 1] = f2bs(a1);
      }
      *(bf16x8*)(t2s + rr * 48 + 8 * g) = pk;
    }
  }
  __syncthreads();

  // phase 4: vertical down-FIR (stride 2) -> t3 [64][48] bf16, 8-col groups
  #pragma unroll
  for (int p = 0; p < 2; ++p) {
    int e = p * 256 + t;
    if (e < 384) {                        // 64 rows x 6 groups
      int pp = e / 6, cg = e - pp * 6;
      const short* col = t2s + (2 * pp) * 48 + 8 * cg;
      float a[8] = {0.f, 0.f, 0.f, 0.f, 0.f, 0.f, 0.f, 0.f};
      #pragma unroll
      for (int j = 0; j < 12; ++j) {
        float cf = ft.f[j];
        bf16x8 v = *(const bf16x8*)(col + j * 48);
        #pragma unroll
        for (int k = 0; k < 8; ++k) a[k] += cf * bf2f(v[k]);
      }
      bf16x8 pk;
      #pragma unroll
      for (int k = 0; k < 8; ++k) pk[k] = f2bs(a[k]);
      *(bf16x8*)(t3s + pp * 48 + 8 * cg) = pk;
    }
  }
  __syncthreads();

  // phase 5: horizontal down-FIR (stride 2) + store f32, 4 outs/thread
  {
    int pp = t >> 2, v = t & 3;           // 64 rows x 4 quads
    const short* row = t3s + pp * 48 + 8 * v;
    float w[20];
    #pragma unroll
    for (int q = 0; q < 5; ++q) {
      short4v x = *(const short4v*)(row + 4 * q);
      #pragma unroll
      for (int k = 0; k < 4; ++k) w[4 * q + k] = bf2f(x[k]);
    }
    float a0 = 0.f, a1 = 0.f, a2 = 0.f, a3 = 0.f;
    #pragma unroll
    for (int j = 0; j < 12; ++j) {
      float cf = ft.f[j];
      a0 += cf * w[j]; a1 += cf * w[j + 2]; a2 += cf * w[j + 4]; a3 += cf * w[j + 6];
    }
    *(float4*)&out[img * 4096 + pp * 64 + c0 + 4 * v] = make_float4(a0, a1, a2, a3);
  }
}

// ---------- host ----------
static double bessel_i0(double x) {
  double q = x * x * 0.25, term = 1.0, sum = 1.0;
  for (int k = 1; k < 64; ++k) {
    term *= q / ((double)k * (double)k);
    sum += term;
    if (term < sum * 1e-18) break;
  }
  return sum;
}

extern "C" void kernel_launch(void* const* d_in, const int* in_sizes, int n_in,
                              void* d_out, int out_size, void* d_ws, size_t ws_size,
                              hipStream_t stream) {
  const float* x   = (const float*)d_in[0];
  const float* w   = (const float*)d_in[1];
  const float* aw  = (const float*)d_in[2];
  const float* ab  = (const float*)d_in[3];
  const float* cw  = (const float*)d_in[4];
  const float* cb  = (const float*)d_in[5];
  const float* ema = (const float*)d_in[6];
  float* out = (float*)d_out;
  char* ws = (char*)d_ws;

  float* styles        = (float*)(ws + 0);          // 16 KB
  float* scal          = (float*)(ws + 16384);      // 16 B
  float* wsq           = (float*)(ws + 16640);      // 256 KB
  float* dco           = (float*)(ws + 278784);     // 16 KB
  __hip_bfloat16* wbt  = (__hip_bfloat16*)(ws + 295168);   // 1.18 MB  [9][256][256]
  unsigned short* xp   = (unsigned short*)(ws + 1474816);  // 37.9 MB  [16][68][68][256]
  unsigned short* y    = (unsigned short*)(ws + 39354624); // 35.7 MB  [16][256][66][66] bf16

  // firwin(12, 16, width=32, fs=128) with Kaiser window (double precision)
  Filt ft;
  {
    double atten = 2.285 * 11.0 * M_PI * 0.5 + 7.95;
    double beta;
    if (atten > 50.0) beta = 0.1102 * (atten - 8.7);
    else if (atten > 21.0) beta = 0.5842 * pow(atten - 21.0, 0.4) + 0.07886 * (atten - 21.0);
    else beta = 0.0;
    double i0b = bessel_i0(beta);
    double h[12], ssum = 0.0;
    for (int n = 0; n < 12; ++n) {
      double xx = ((double)n - 5.5) / 5.5;
      double win = bessel_i0(beta * sqrt(1.0 - xx * xx)) / i0b;
      double mm = ((double)n - 5.5) * 0.25;
      double snc = sin(M_PI * mm) / (M_PI * mm);
      h[n] = 0.25 * snc * win;
      ssum += h[n];
    }
    for (int n = 0; n < 12; ++n) ft.f[n] = (float)(h[n] / ssum);
  }

  k_styles <<<16, 256, 0, stream>>>(w, aw, ab, styles);
  k_scalars<<<1, 256, 0, stream>>>(styles, ema, scal);
  k_wnorm  <<<256, 256, 0, stream>>>(cw, wsq, wbt);
  k_dcoefs <<<16, 256, 0, stream>>>(styles, wsq, scal, dco);
  k_xpad   <<<dim3(4, 68, 16), 256, 0, stream>>>(x, styles, scal, xp);
  k_conv   <<<1090, 256, 0, stream>>>(xp, (const unsigned short*)wbt, dco, cb, y);
  k_lrelu  <<<16384, 256, 0, stream>>>(y, out, ft);
}

// Round 14
// 266.300 us; speedup vs baseline: 1.6869x; 1.2091x over previous
//
#include <hip/hip_runtime.h>
#include <hip/hip_bf16.h>
#include <math.h>

// StyleGAN3 SynthesisLayer forward, MI355X.
// B=16, CIN=COUT=256, H=W=64, K=3, up=2 down=2 taps=12, conv out 66x66,
// up-FIR out 138x138, final out 64x64.

typedef __attribute__((ext_vector_type(8))) short bf16x8;
typedef __attribute__((ext_vector_type(4))) float f32x4;
typedef _Float16 h2 __attribute__((ext_vector_type(2)));

#define NM 69696         // 16*66*66 flattened conv-output positions
#define SPI 4356         // 66*66 spatial per image

__device__ inline void gload16(const void* g, void* l) {
  __builtin_amdgcn_global_load_lds((const __attribute__((address_space(1))) void*)g,
                                   (__attribute__((address_space(3))) void*)l, 16, 0, 0);
}
static __device__ __forceinline__ short f2hs(float f) {
  _Float16 h = (_Float16)f;
  return *(short*)&h;
}
static __device__ __forceinline__ h2 h2bc(unsigned u) { return __builtin_bit_cast(h2, u); }
static __device__ __forceinline__ unsigned u32bc(h2 v) { return __builtin_bit_cast(unsigned, v); }
static __device__ __forceinline__ h2 h2splat(float f) {
  _Float16 x = (_Float16)f; h2 r; r[0] = x; r[1] = x; return r;
}

// ---------- styles = w @ aw^T / sqrt(512) + ab ----------
__global__ __launch_bounds__(256) void k_styles(
    const float* __restrict__ w, const float* __restrict__ aw,
    const float* __restrict__ ab, float* __restrict__ styles) {
  __shared__ float lw[512];
  int b = blockIdx.x, t = threadIdx.x;
  lw[t] = w[b * 512 + t];
  lw[t + 256] = w[b * 512 + t + 256];
  __syncthreads();
  const float* row = aw + (long)t * 512;
  float acc = 0.f;
  #pragma unroll 4
  for (int d = 0; d < 512; ++d) acc += row[d] * lw[d];
  styles[b * 256 + t] = acc * 0.04419417382415922f + ab[t];
}

// ---------- scal[0] = 1/mean(styles^2), scal[1] = rsqrt(ema) ----------
__global__ __launch_bounds__(256) void k_scalars(
    const float* __restrict__ styles, const float* __restrict__ ema,
    float* __restrict__ scal) {
  __shared__ float red[256];
  int t = threadIdx.x;
  float s = 0.f;
  #pragma unroll
  for (int k = 0; k < 16; ++k) { float v = styles[t + k * 256]; s += v * v; }
  red[t] = s; __syncthreads();
  for (int off = 128; off > 0; off >>= 1) {
    if (t < off) red[t] += red[t + off];
    __syncthreads();
  }
  if (t == 0) { scal[0] = 4096.0f / red[0]; scal[1] = 1.0f / sqrtf(ema[0]); }
}

// ---------- per-o weight norm; wsq[o][i]; wbt[tap][o][i] bf16 ----------
__global__ __launch_bounds__(256) void k_wnorm(
    const float* __restrict__ cw, float* __restrict__ wsq,
    __hip_bfloat16* __restrict__ wbt) {
  __shared__ float red[256];
  __shared__ float lws, lws2;
  int o = blockIdx.x, t = threadIdx.x;
  const float* base = cw + o * 2304;
  float s = 0.f;
  #pragma unroll
  for (int k = 0; k < 9; ++k) { float v = base[t + k * 256]; s += v * v; }
  red[t] = s; __syncthreads();
  for (int off = 128; off > 0; off >>= 1) {
    if (t < off) red[t] += red[t + off];
    __syncthreads();
  }
  if (t == 0) { lws2 = 2304.0f / red[0]; lws = sqrtf(lws2); }
  __syncthreads();
  const float* r9 = base + t * 9;
  float s9 = 0.f;
  #pragma unroll
  for (int k = 0; k < 9; ++k) s9 += r9[k] * r9[k];
  wsq[o * 256 + t] = lws2 * s9;
  #pragma unroll
  for (int tap = 0; tap < 9; ++tap)
    wbt[(tap * 256 + o) * 256 + t] = __float2bfloat16(r9[tap] * lws);
}

// ---------- dcoefs[b][o] = rsqrt(sum_i s^2 * wsq + 1e-8) * input_gain ----------
__global__ __launch_bounds__(256) void k_dcoefs(
    const float* __restrict__ styles, const float* __restrict__ wsq,
    const float* __restrict__ scal, float* __restrict__ dco) {
  __shared__ float sn2[256];
  int b = blockIdx.x, t = threadIdx.x;
  float v = styles[b * 256 + t];
  sn2[t] = v * v * scal[0];
  __syncthreads();
  const float* wr = wsq + t * 256;
  float acc = 0.f;
  #pragma unroll 4
  for (int i = 0; i < 256; ++i) acc += sn2[i] * wr[i];
  dco[b * 256 + t] = (1.0f / sqrtf(acc + 1e-8f)) * scal[1];
}

// ---------- xs_pad[b][68][68][256] bf16, NHWC, style-scaled ----------
__global__ __launch_bounds__(256) void k_xpad(
    const float* __restrict__ x, const float* __restrict__ styles,
    const float* __restrict__ scal, unsigned short* __restrict__ xp) {
  __shared__ float lx[64 * 65];
  __shared__ float sc[64];
  int ig = blockIdx.x, hp = blockIdx.y, b = blockIdx.z, t = threadIdx.x;
  int i0 = ig * 64;
  float ss = sqrtf(scal[0]);
  if (t < 64) sc[t] = styles[b * 256 + i0 + t] * ss;
  int h = hp - 2;
  bool inh = (hp >= 2) && (hp < 66);
  if (inh) {
    #pragma unroll
    for (int p = 0; p < 16; ++p) {
      int idx = p * 256 + t; int i = idx >> 6, w = idx & 63;
      lx[i * 65 + w] = x[((b * 256 + i0 + i) * 64 + h) * 64 + w];
    }
  }
  __syncthreads();
  unsigned short* dst = xp + ((long)(b * 68 + hp) * 68) * 256 + i0;
  #pragma unroll
  for (int p = 0; p < 17; ++p) {
    int idx = p * 256 + t; int wp = idx >> 6, i = idx & 63;
    float v = 0.f;
    if (inh && wp >= 2 && wp < 66) v = lx[i * 65 + (wp - 2)] * sc[i];
    __hip_bfloat16 bv = __float2bfloat16(v);
    dst[wp * 256 + i] = *(unsigned short*)&bv;
  }
}

// ---------- conv: R11-proven GEMM (XCD swizzle + launch_bounds(256,4)) ----------
// Epilogue writes y as FP16 (feeds packed-half lrelu); otherwise frozen.
__global__ __launch_bounds__(256, 4) void k_conv(
    const unsigned short* __restrict__ xp, const unsigned short* __restrict__ wbt,
    const float* __restrict__ dco, const float* __restrict__ bias,
    unsigned short* __restrict__ y) {
  __shared__ __align__(16) unsigned short As[128 * 64];
  __shared__ __align__(16) unsigned short Bs[128 * 64];
  const int t = threadIdx.x;
  const int lane = t & 63;
  const int wave = t >> 6;
  const int wm = wave >> 1, wn = wave & 1;

  // bijective XCD swizzle: nwg=1090 = 8*136 + 2 (xcd 0,1 get 137)
  const int f = blockIdx.x;
  const int xcd = f & 7, pos = f >> 3;
  const int wgid = (xcd < 2 ? xcd * 137 : 274 + (xcd - 2) * 136) + pos;
  const int o0 = (wgid & 1) * 128;
  const int m0 = (wgid >> 1) * 128;

  int abase[4], bbase[4];
  #pragma unroll
  for (int j = 0; j < 4; ++j) {
    int task = j * 256 + t;
    int lm = task >> 3, ch = task & 7;
    int csrc = ch ^ (lm & 7);
    int m = m0 + lm; if (m > NM - 1) m = NM - 1;
    int b = m / SPI; int sp = m - b * SPI;
    int r = sp / 66; int c = sp - r * 66;
    abase[j] = (((b * 68 + r) * 68 + c) << 9) + (csrc << 4);   // bytes
    bbase[j] = ((o0 + lm) << 9) + (csrc << 4);                 // bytes
  }
  f32x4 acc[4][4] = {};
  const char* xb = (const char*)xp;
  const char* wb = (const char*)wbt;
  char* asb = (char*)As;
  char* bsb = (char*)Bs;

  for (int kk = 0; kk < 36; ++kk) {
    int tap = kk >> 2;
    int ch0b = (kk & 3) << 7;            // ch0 * 2 bytes
    int ky = tap / 3, kx = tap - ky * 3;
    int aoff = ((ky * 68 + kx) << 9) + ch0b;
    int boff = (tap << 17) + ch0b;
    #pragma unroll
    for (int j = 0; j < 4; ++j) {
      gload16(xb + abase[j] + aoff, asb + ((j * 256 + t) << 4));
      gload16(wb + bbase[j] + boff, bsb + ((j * 256 + t) << 4));
    }
    __syncthreads();   // drains vmcnt -> tiles visible
    #pragma unroll
    for (int h = 0; h < 2; ++h) {
      bf16x8 av[4], bv[4];
      #pragma unroll
      for (int fm = 0; fm < 4; ++fm) {
        int arow = wm * 64 + fm * 16 + (lane & 15);
        int chk = ((h << 2) + (lane >> 4)) ^ (arow & 7);
        av[fm] = *(const bf16x8*)(asb + arow * 128 + chk * 16);
      }
      #pragma unroll
      for (int fn = 0; fn < 4; ++fn) {
        int brow = wn * 64 + fn * 16 + (lane & 15);
        int chk = ((h << 2) + (lane >> 4)) ^ (brow & 7);
        bv[fn] = *(const bf16x8*)(bsb + brow * 128 + chk * 16);
      }
      #pragma unroll
      for (int fm = 0; fm < 4; ++fm)
        #pragma unroll
        for (int fn = 0; fn < 4; ++fn)
          acc[fm][fn] = __builtin_amdgcn_mfma_f32_16x16x32_bf16(
              av[fm], bv[fn], acc[fm][fn], 0, 0, 0);
    }
    __syncthreads();   // readers done before next overwrite
  }

  // Epilogue: scale + bias, transpose via LDS slab [128m][17], write NCHW fp16.
  float* slab = (float*)As;
  #pragma unroll
  for (int s = 0; s < 8; ++s) {
    if (wn == (s >> 2)) {
      const int sfn = s & 3;
      int ocol = lane & 15;
      int og = o0 + s * 16 + ocol;
      float bo = bias[og];
      #pragma unroll
      for (int fm = 0; fm < 4; ++fm) {
        #pragma unroll
        for (int j = 0; j < 4; ++j) {
          int lm = wm * 64 + fm * 16 + ((lane >> 4) << 2) + j;
          int m = m0 + lm;
          float v = acc[fm][sfn][j];
          if (m < NM) {
            int b = m / SPI;
            v = v * dco[b * 256 + og] + bo;
          }
          slab[lm * 17 + ocol] = v;
        }
      }
    }
    __syncthreads();
    int oc2 = t >> 4;
    int og2 = o0 + s * 16 + oc2;
    #pragma unroll
    for (int p = 0; p < 8; ++p) {
      int lm = (t & 15) + p * 16;
      int m = m0 + lm;
      if (m < NM) {
        int b = m / SPI; int sp = m - b * SPI;
        y[(long)(b * 256 + og2) * SPI + sp] =
            (unsigned short)f2hs(slab[lm * 17 + oc2]);
      }
    }
    __syncthreads();
  }
}

// ---------- filtered_lrelu v4b: fp16 packed datapath via _Float16 vectors ----------
// R11 diagnosis: VALUBusy 95% -- FMA + bf16<->f32 conversions are the wall.
// fp16 LDS + packed h2 ops (v_pk_fma_f16 via contraction): FMA instrs halve,
// conversions vanish, precision improves (fp16 11-bit mantissa, |vals|<=256).
// R12 lesson: __hmax2/__hmul2 collide with hip_bf16.h overloads -> use
// native _Float16 ext-vectors + __builtin_elementwise_{max,min} instead.
// Layouts (shorts/row, rows 16B-aligned): t1[138][40], t2[138][56];
// bufY[78][56] overlays t2 (6 zero rows top/bottom kill vertical guards);
// t3[64][56] overlays t1. LDS 26.5KB -> 6 blocks/CU.
struct Filt { float f[12]; };

__global__ __launch_bounds__(256) void k_lrelu(
    const unsigned short* __restrict__ y, float* __restrict__ out, Filt ft) {
  __shared__ __align__(16) short t1s[138 * 40];   // 11040 B
  __shared__ __align__(16) short t2s[138 * 56];   // 15456 B
  short* bufYs = t2s;                             // [78][56]
  short* t3s = t1s;                               // [64][56]
  const int t = threadIdx.x;
  const int strip = blockIdx.x & 3;
  const long img = blockIdx.x >> 2;
  const int c0 = strip * 16;
  const unsigned short* ysrc = y + img * SPI;

  const h2 z2 = h2splat(0.f);
  h2 e2[6], o2[6], c3[6], c4[12];
  #pragma unroll
  for (int j = 0; j < 6; ++j) {
    e2[j] = h2splat(2.f * ft.f[2 * j]);
    o2[j] = h2splat(2.f * ft.f[2 * j + 1]);
    h2 c; c[0] = (_Float16)(2.f * ft.f[2 * j + 1]); c[1] = (_Float16)(2.f * ft.f[2 * j]);
    c3[j] = c;                            // {lo: odd tap, hi: even tap}, 2x folded
  }
  #pragma unroll
  for (int j = 0; j < 12; ++j) c4[j] = h2splat(ft.f[j]);
  const h2 k02 = h2splat(0.2f);
  const h2 ks2 = h2splat(1.41421356237f);
  const h2 kpc = h2splat(256.f);
  const h2 knc = h2splat(-256.f);

  // phase 1: bufY [78][56] fp16; rows 6..71 = y rows 0..65; cols c0-4..c0+21
  // -> slots 0..25, rest zero.
  #pragma unroll
  for (int p = 0; p < 2; ++p) {
    int e = p * 256 + t;
    if (e < 312) {
      int rp = e >> 2, cg = e & 3;
      int r = rp - 6;
      int cbase = c0 - 4 + 8 * cg;
      uint4 pk = make_uint4(0u, 0u, 0u, 0u);
      if (r >= 0 && r < 66) {
        if (cg < 3 && cbase >= 0 && cbase + 7 <= 65) {
          pk = *(const uint4*)(ysrc + r * 66 + cbase);
        } else {
          unsigned v[8];
          #pragma unroll
          for (int k = 0; k < 8; ++k) {
            int lc = 8 * cg + k, c = c0 - 4 + lc;
            v[k] = (lc < 26 && c >= 0 && c < 66) ? (unsigned)ysrc[r * 66 + c] : 0u;
          }
          pk.x = v[0] | (v[1] << 16); pk.y = v[2] | (v[3] << 16);
          pk.z = v[4] | (v[5] << 16); pk.w = v[6] | (v[7] << 16);
        }
      }
      *(uint4*)(bufYs + rp * 56 + 8 * cg) = pk;
    }
  }
  __syncthreads();

  // phase 2: vertical up-FIR, row pairs -> t1 [138][40]
  // out rows (2rq, 2rq+1) share window bufY rows rq+2..rq+7 (same yr0);
  // even row uses odd taps (o2), odd row uses even taps (e2).
  #pragma unroll
  for (int p = 0; p < 2; ++p) {
    int e = p * 256 + t;
    if (e < 276) {                        // 69 row-pairs x 4 col-groups
      int rq = e >> 2, cg = e & 3;
      const short* base = bufYs + (rq + 2) * 56 + 8 * cg;
      h2 a0[4], a1[4];
      #pragma unroll
      for (int k = 0; k < 4; ++k) { a0[k] = z2; a1[k] = z2; }
      #pragma unroll
      for (int j = 0; j < 6; ++j) {
        uint4 u = *(const uint4*)(base + j * 56);
        h2 v0 = h2bc(u.x), v1 = h2bc(u.y), v2 = h2bc(u.z), v3 = h2bc(u.w);
        a0[0] = v0 * o2[j] + a0[0]; a1[0] = v0 * e2[j] + a1[0];
        a0[1] = v1 * o2[j] + a0[1]; a1[1] = v1 * e2[j] + a1[1];
        a0[2] = v2 * o2[j] + a0[2]; a1[2] = v2 * e2[j] + a1[2];
        a0[3] = v3 * o2[j] + a0[3]; a1[3] = v3 * e2[j] + a1[3];
      }
      uint4 s0, s1;
      s0.x = u32bc(a0[0]); s0.y = u32bc(a0[1]); s0.z = u32bc(a0[2]); s0.w = u32bc(a0[3]);
      s1.x = u32bc(a1[0]); s1.y = u32bc(a1[1]); s1.z = u32bc(a1[2]); s1.w = u32bc(a1[3]);
      *(uint4*)(t1s + (2 * rq) * 40 + 8 * cg) = s0;
      *(uint4*)(t1s + (2 * rq + 1) * 40 + 8 * cg) = s1;
    }
  }
  __syncthreads();

  // phase 3: horizontal up-FIR + lrelu*sqrt2 + clamp -> t2 [138][56]
  // group g: out col pairs (8g+2i, 8g+2i+1), i=0..3, window t1 cols 4g..4g+8.
  #pragma unroll
  for (int p = 0; p < 4; ++p) {
    int e = p * 256 + t;
    if (e < 828) {                        // 138 rows x 6 groups
      int rr = e / 6, g = e - rr * 6;
      const short* tr = t1s + rr * 40 + 4 * g;
      h2 h[5];
      #pragma unroll
      for (int q = 0; q < 5; ++q) h[q] = h2bc(*(const unsigned*)(tr + 2 * q));
      h2 r[4];
      #pragma unroll
      for (int i = 0; i < 4; ++i) {
        h2 a = z2;
        #pragma unroll
        for (int j = 0; j < 6; ++j) {
          int k = i + j;
          h2 src = h[k >> 1];
          h2 wb = (k & 1) ? __builtin_shufflevector(src, src, 1, 1)
                          : __builtin_shufflevector(src, src, 0, 0);
          a = wb * c3[j] + a;
        }
        h2 m = __builtin_elementwise_max(a, a * k02);
        m = m * ks2;
        m = __builtin_elementwise_min(__builtin_elementwise_max(m, knc), kpc);
        r[i] = m;
      }
      uint4 s;
      s.x = u32bc(r[0]); s.y = u32bc(r[1]); s.z = u32bc(r[2]); s.w = u32bc(r[3]);
      *(uint4*)(t2s + rr * 56 + 8 * g) = s;
    }
  }
  __syncthreads();

  // phase 4: vertical down-FIR (stride 2) -> t3 [64][56]
  #pragma unroll
  for (int p = 0; p < 2; ++p) {
    int e = p * 256 + t;
    if (e < 384) {                        // 64 rows x 6 groups
      int pp = e / 6, cg = e - pp * 6;
      const short* col = t2s + (2 * pp) * 56 + 8 * cg;
      h2 a[4];
      #pragma unroll
      for (int k = 0; k < 4; ++k) a[k] = z2;
      #pragma unroll
      for (int j = 0; j < 12; ++j) {
        uint4 u = *(const uint4*)(col + j * 56);
        a[0] = h2bc(u.x) * c4[j] + a[0];
        a[1] = h2bc(u.y) * c4[j] + a[1];
        a[2] = h2bc(u.z) * c4[j] + a[2];
        a[3] = h2bc(u.w) * c4[j] + a[3];
      }
      uint4 s;
      s.x = u32bc(a[0]); s.y = u32bc(a[1]); s.z = u32bc(a[2]); s.w = u32bc(a[3]);
      *(uint4*)(t3s + pp * 56 + 8 * cg) = s;
    }
  }
  __syncthreads();

  // phase 5: horizontal down-FIR (stride 2) + store f32, 4 outs/thread
  {
    int pp = t >> 2, v = t & 3;           // 64 rows x 4 quads
    const short* row = t3s + pp * 56 + 8 * v;
    h2 h[9];
    #pragma unroll
    for (int q = 0; q < 9; ++q) h[q] = h2bc(*(const unsigned*)(row + 2 * q));
    h2 aA = z2, aB = z2;                  // pairs (4v,4v+1), (4v+2,4v+3)
    #pragma unroll
    for (int j = 0; j < 12; ++j) {
      int q = j >> 1;
      h2 wA = (j & 1) ? __builtin_shufflevector(h[q], h[q + 1], 1, 3)
                      : __builtin_shufflevector(h[q], h[q + 1], 0, 2);
      h2 wB = (j & 1) ? __builtin_shufflevector(h[q + 2], h[q + 3], 1, 3)
                      : __builtin_shufflevector(h[q + 2], h[q + 3], 0, 2);
      aA = wA * c4[j] + aA;
      aB = wB * c4[j] + aB;
    }
    *(float4*)&out[img * 4096 + pp * 64 + c0 + 4 * v] =
        make_float4((float)aA[0], (float)aA[1], (float)aB[0], (float)aB[1]);
  }
}

// ---------- host ----------
static double bessel_i0(double x) {
  double q = x * x * 0.25, term = 1.0, sum = 1.0;
  for (int k = 1; k < 64; ++k) {
    term *= q / ((double)k * (double)k);
    sum += term;
    if (term < sum * 1e-18) break;
  }
  return sum;
}

extern "C" void kernel_launch(void* const* d_in, const int* in_sizes, int n_in,
                              void* d_out, int out_size, void* d_ws, size_t ws_size,
                              hipStream_t stream) {
  const float* x   = (const float*)d_in[0];
  const float* w   = (const float*)d_in[1];
  const float* aw  = (const float*)d_in[2];
  const float* ab  = (const float*)d_in[3];
  const float* cw  = (const float*)d_in[4];
  const float* cb  = (const float*)d_in[5];
  const float* ema = (const float*)d_in[6];
  float* out = (float*)d_out;
  char* ws = (char*)d_ws;

  float* styles        = (float*)(ws + 0);          // 16 KB
  float* scal          = (float*)(ws + 16384);      // 16 B
  float* wsq           = (float*)(ws + 16640);      // 256 KB
  float* dco           = (float*)(ws + 278784);     // 16 KB
  __hip_bfloat16* wbt  = (__hip_bfloat16*)(ws + 295168);   // 1.18 MB  [9][256][256]
  unsigned short* xp   = (unsigned short*)(ws + 1474816);  // 37.9 MB  [16][68][68][256]
  unsigned short* y    = (unsigned short*)(ws + 39354624); // 35.7 MB  [16][256][66][66] fp16

  // firwin(12, 16, width=32, fs=128) with Kaiser window (double precision)
  Filt ft;
  {
    double atten = 2.285 * 11.0 * M_PI * 0.5 + 7.95;
    double beta;
    if (atten > 50.0) beta = 0.1102 * (atten - 8.7);
    else if (atten > 21.0) beta = 0.5842 * pow(atten - 21.0, 0.4) + 0.07886 * (atten - 21.0);
    else beta = 0.0;
    double i0b = bessel_i0(beta);
    double h[12], ssum = 0.0;
    for (int n = 0; n < 12; ++n) {
      double xx = ((double)n - 5.5) / 5.5;
      double win = bessel_i0(beta * sqrt(1.0 - xx * xx)) / i0b;
      double mm = ((double)n - 5.5) * 0.25;
      double snc = sin(M_PI * mm) / (M_PI * mm);
      h[n] = 0.25 * snc * win;
      ssum += h[n];
    }
    for (int n = 0; n < 12; ++n) ft.f[n] = (float)(h[n] / ssum);
  }

  k_styles <<<16, 256, 0, stream>>>(w, aw, ab, styles);
  k_scalars<<<1, 256, 0, stream>>>(styles, ema, scal);
  k_wnorm  <<<256, 256, 0, stream>>>(cw, wsq, wbt);
  k_dcoefs <<<16, 256, 0, stream>>>(styles, wsq, scal, dco);
  k_xpad   <<<dim3(4, 68, 16), 256, 0, stream>>>(x, styles, scal, xp);
  k_conv   <<<1090, 256, 0, stream>>>(xp, (const unsigned short*)wbt, dco, cb, y);
  k_lrelu  <<<16384, 256, 0, stream>>>(y, out, ft);
}

// Round 15
// 245.441 us; speedup vs baseline: 1.8302x; 1.0850x over previous
//
#include <hip/hip_runtime.h>
#include <hip/hip_bf16.h>
#include <math.h>

// StyleGAN3 SynthesisLayer forward, MI355X.
// B=16, CIN=COUT=256, H=W=64, K=3, up=2 down=2 taps=12, conv out 66x66,
// up-FIR out 138x138, final out 64x64.

typedef __attribute__((ext_vector_type(8))) short bf16x8;
typedef __attribute__((ext_vector_type(4))) float f32x4;
typedef _Float16 h2 __attribute__((ext_vector_type(2)));

#define NM 69696         // 16*66*66 flattened conv-output positions
#define SPI 4356         // 66*66 spatial per image

__device__ inline void gload16(const void* g, void* l) {
  __builtin_amdgcn_global_load_lds((const __attribute__((address_space(1))) void*)g,
                                   (__attribute__((address_space(3))) void*)l, 16, 0, 0);
}
static __device__ __forceinline__ short f2hs(float f) {
  _Float16 h = (_Float16)f;
  return *(short*)&h;
}
static __device__ __forceinline__ h2 h2bc(unsigned u) { return __builtin_bit_cast(h2, u); }
static __device__ __forceinline__ unsigned u32bc(h2 v) { return __builtin_bit_cast(unsigned, v); }
static __device__ __forceinline__ h2 h2splat(float f) {
  _Float16 x = (_Float16)f; h2 r; r[0] = x; r[1] = x; return r;
}

// ---------- styles = w @ aw^T / sqrt(512) + ab ----------
__global__ __launch_bounds__(256) void k_styles(
    const float* __restrict__ w, const float* __restrict__ aw,
    const float* __restrict__ ab, float* __restrict__ styles) {
  __shared__ float lw[512];
  int b = blockIdx.x, t = threadIdx.x;
  lw[t] = w[b * 512 + t];
  lw[t + 256] = w[b * 512 + t + 256];
  __syncthreads();
  const float* row = aw + (long)t * 512;
  float acc = 0.f;
  #pragma unroll 4
  for (int d = 0; d < 512; ++d) acc += row[d] * lw[d];
  styles[b * 256 + t] = acc * 0.04419417382415922f + ab[t];
}

// ---------- scal[0] = 1/mean(styles^2), scal[1] = rsqrt(ema) ----------
__global__ __launch_bounds__(256) void k_scalars(
    const float* __restrict__ styles, const float* __restrict__ ema,
    float* __restrict__ scal) {
  __shared__ float red[256];
  int t = threadIdx.x;
  float s = 0.f;
  #pragma unroll
  for (int k = 0; k < 16; ++k) { float v = styles[t + k * 256]; s += v * v; }
  red[t] = s; __syncthreads();
  for (int off = 128; off > 0; off >>= 1) {
    if (t < off) red[t] += red[t + off];
    __syncthreads();
  }
  if (t == 0) { scal[0] = 4096.0f / red[0]; scal[1] = 1.0f / sqrtf(ema[0]); }
}

// ---------- per-o weight norm; wsq[o][i]; wbt[tap][o][i] bf16 ----------
__global__ __launch_bounds__(256) void k_wnorm(
    const float* __restrict__ cw, float* __restrict__ wsq,
    __hip_bfloat16* __restrict__ wbt) {
  __shared__ float red[256];
  __shared__ float lws, lws2;
  int o = blockIdx.x, t = threadIdx.x;
  const float* base = cw + o * 2304;
  float s = 0.f;
  #pragma unroll
  for (int k = 0; k < 9; ++k) { float v = base[t + k * 256]; s += v * v; }
  red[t] = s; __syncthreads();
  for (int off = 128; off > 0; off >>= 1) {
    if (t < off) red[t] += red[t + off];
    __syncthreads();
  }
  if (t == 0) { lws2 = 2304.0f / red[0]; lws = sqrtf(lws2); }
  __syncthreads();
  const float* r9 = base + t * 9;
  float s9 = 0.f;
  #pragma unroll
  for (int k = 0; k < 9; ++k) s9 += r9[k] * r9[k];
  wsq[o * 256 + t] = lws2 * s9;
  #pragma unroll
  for (int tap = 0; tap < 9; ++tap)
    wbt[(tap * 256 + o) * 256 + t] = __float2bfloat16(r9[tap] * lws);
}

// ---------- dcoefs[b][o] = rsqrt(sum_i s^2 * wsq + 1e-8) * input_gain ----------
__global__ __launch_bounds__(256) void k_dcoefs(
    const float* __restrict__ styles, const float* __restrict__ wsq,
    const float* __restrict__ scal, float* __restrict__ dco) {
  __shared__ float sn2[256];
  int b = blockIdx.x, t = threadIdx.x;
  float v = styles[b * 256 + t];
  sn2[t] = v * v * scal[0];
  __syncthreads();
  const float* wr = wsq + t * 256;
  float acc = 0.f;
  #pragma unroll 4
  for (int i = 0; i < 256; ++i) acc += sn2[i] * wr[i];
  dco[b * 256 + t] = (1.0f / sqrtf(acc + 1e-8f)) * scal[1];
}

// ---------- xs_pad[b][68][68][256] bf16, NHWC, style-scaled ----------
__global__ __launch_bounds__(256) void k_xpad(
    const float* __restrict__ x, const float* __restrict__ styles,
    const float* __restrict__ scal, unsigned short* __restrict__ xp) {
  __shared__ float lx[64 * 65];
  __shared__ float sc[64];
  int ig = blockIdx.x, hp = blockIdx.y, b = blockIdx.z, t = threadIdx.x;
  int i0 = ig * 64;
  float ss = sqrtf(scal[0]);
  if (t < 64) sc[t] = styles[b * 256 + i0 + t] * ss;
  int h = hp - 2;
  bool inh = (hp >= 2) && (hp < 66);
  if (inh) {
    #pragma unroll
    for (int p = 0; p < 16; ++p) {
      int idx = p * 256 + t; int i = idx >> 6, w = idx & 63;
      lx[i * 65 + w] = x[((b * 256 + i0 + i) * 64 + h) * 64 + w];
    }
  }
  __syncthreads();
  unsigned short* dst = xp + ((long)(b * 68 + hp) * 68) * 256 + i0;
  #pragma unroll
  for (int p = 0; p < 17; ++p) {
    int idx = p * 256 + t; int wp = idx >> 6, i = idx & 63;
    float v = 0.f;
    if (inh && wp >= 2 && wp < 66) v = lx[i * 65 + (wp - 2)] * sc[i];
    __hip_bfloat16 bv = __float2bfloat16(v);
    dst[wp * 256 + i] = *(unsigned short*)&bv;
  }
}

// ---------- conv v8: BN=64 re-partition for occupancy ----------
// R13 diagnosis: occupancy is the only lever that has moved conv (191->131);
// acc[4][4]=64 AGPR + 60 VGPR = 124 regs caps at 4 waves/EU. This version:
// BM=128 x BN=64 tiles (grid 2180; 4 o-quarters share each m-tile's A in L2),
// 4 waves (2m x 2n), per-wave 64x32 -> acc[4][2] = 32 AGPR. LDS 16K+8K=24KB.
// ~88 regs -> 5 waves/EU -> 5 blocks = 20 waves/CU (62%), 2.4x current.
// A-side staging/swizzle identical to proven R1 code; B-side same pattern at
// half height; 2-barrier schedule and epilogue unchanged.
__global__ __launch_bounds__(256, 5) void k_conv(
    const unsigned short* __restrict__ xp, const unsigned short* __restrict__ wbt,
    const float* __restrict__ dco, const float* __restrict__ bias,
    unsigned short* __restrict__ y) {
  __shared__ __align__(16) unsigned short As[128 * 64];   // 16 KB
  __shared__ __align__(16) unsigned short Bs[64 * 64];    // 8 KB
  const int t = threadIdx.x;
  const int lane = t & 63;
  const int wave = t >> 6;
  const int wm = wave >> 1, wn = wave & 1;   // 2m x 2n

  // bijective XCD swizzle: nwg=2180 = 8*272 + 4 (xcd 0..3 get 273)
  const int f = blockIdx.x;
  const int xcd = f & 7, pos = f >> 3;
  const int wgid = (xcd < 4 ? xcd * 273 : 1092 + (xcd - 4) * 272) + pos;
  const int o0 = (wgid & 3) * 64;
  const int m0 = (wgid >> 2) * 128;

  // A staging (identical to R1): 1024 slots, 4/thread
  int abase[4];
  #pragma unroll
  for (int j = 0; j < 4; ++j) {
    int task = j * 256 + t;
    int lm = task >> 3, ch = task & 7;
    int csrc = ch ^ (lm & 7);
    int m = m0 + lm; if (m > NM - 1) m = NM - 1;
    int b = m / SPI; int sp = m - b * SPI;
    int r = sp / 66; int c = sp - r * 66;
    abase[j] = (((b * 68 + r) * 68 + c) << 9) + (csrc << 4);   // bytes
  }
  // B staging: 512 slots (64 o-rows x 8 chunks), 2/thread
  int bbase[2];
  #pragma unroll
  for (int j = 0; j < 2; ++j) {
    int task = j * 256 + t;
    int lm = task >> 3, ch = task & 7;
    int csrc = ch ^ (lm & 7);
    bbase[j] = ((o0 + lm) << 9) + (csrc << 4);                 // bytes
  }
  f32x4 acc[4][2] = {};
  const char* xb = (const char*)xp;
  const char* wb = (const char*)wbt;
  char* asb = (char*)As;
  char* bsb = (char*)Bs;

  for (int kk = 0; kk < 36; ++kk) {
    int tap = kk >> 2;
    int ch0b = (kk & 3) << 7;            // ch0 * 2 bytes
    int ky = tap / 3, kx = tap - ky * 3;
    int aoff = ((ky * 68 + kx) << 9) + ch0b;
    int boff = (tap << 17) + ch0b;
    #pragma unroll
    for (int j = 0; j < 4; ++j)
      gload16(xb + abase[j] + aoff, asb + ((j * 256 + t) << 4));
    #pragma unroll
    for (int j = 0; j < 2; ++j)
      gload16(wb + bbase[j] + boff, bsb + ((j * 256 + t) << 4));
    __syncthreads();   // drains vmcnt -> tiles visible
    #pragma unroll
    for (int h = 0; h < 2; ++h) {
      bf16x8 av[4], bv[2];
      #pragma unroll
      for (int fm = 0; fm < 4; ++fm) {
        int arow = wm * 64 + fm * 16 + (lane & 15);
        int chk = ((h << 2) + (lane >> 4)) ^ (arow & 7);
        av[fm] = *(const bf16x8*)(asb + arow * 128 + chk * 16);
      }
      #pragma unroll
      for (int fn = 0; fn < 2; ++fn) {
        int brow = wn * 32 + fn * 16 + (lane & 15);
        int chk = ((h << 2) + (lane >> 4)) ^ (brow & 7);
        bv[fn] = *(const bf16x8*)(bsb + brow * 128 + chk * 16);
      }
      #pragma unroll
      for (int fm = 0; fm < 4; ++fm)
        #pragma unroll
        for (int fn = 0; fn < 2; ++fn)
          acc[fm][fn] = __builtin_amdgcn_mfma_f32_16x16x32_bf16(
              av[fm], bv[fn], acc[fm][fn], 0, 0, 0);
    }
    __syncthreads();   // readers done before next overwrite
  }

  // Epilogue: scale + bias, transpose via LDS slab [128m][17], write NCHW fp16.
  float* slab = (float*)As;
  #pragma unroll
  for (int s = 0; s < 4; ++s) {
    if (wn == (s >> 1)) {
      const int sfn = s & 1;
      int ocol = lane & 15;
      int og = o0 + s * 16 + ocol;
      float bo = bias[og];
      #pragma unroll
      for (int fm = 0; fm < 4; ++fm) {
        #pragma unroll
        for (int j = 0; j < 4; ++j) {
          int lm = wm * 64 + fm * 16 + ((lane >> 4) << 2) + j;
          int m = m0 + lm;
          float v = acc[fm][sfn][j];
          if (m < NM) {
            int b = m / SPI;
            v = v * dco[b * 256 + og] + bo;
          }
          slab[lm * 17 + ocol] = v;
        }
      }
    }
    __syncthreads();
    int oc2 = t >> 4;
    int og2 = o0 + s * 16 + oc2;
    #pragma unroll
    for (int p = 0; p < 8; ++p) {
      int lm = (t & 15) + p * 16;
      int m = m0 + lm;
      if (m < NM) {
        int b = m / SPI; int sp = m - b * SPI;
        y[(long)(b * 256 + og2) * SPI + sp] =
            (unsigned short)f2hs(slab[lm * 17 + oc2]);
      }
    }
    __syncthreads();
  }
}

// ---------- filtered_lrelu v4b: fp16 packed datapath (R13, unchanged) ----------
struct Filt { float f[12]; };

__global__ __launch_bounds__(256) void k_lrelu(
    const unsigned short* __restrict__ y, float* __restrict__ out, Filt ft) {
  __shared__ __align__(16) short t1s[138 * 40];   // 11040 B
  __shared__ __align__(16) short t2s[138 * 56];   // 15456 B
  short* bufYs = t2s;                             // [78][56]
  short* t3s = t1s;                               // [64][56]
  const int t = threadIdx.x;
  const int strip = blockIdx.x & 3;
  const long img = blockIdx.x >> 2;
  const int c0 = strip * 16;
  const unsigned short* ysrc = y + img * SPI;

  const h2 z2 = h2splat(0.f);
  h2 e2[6], o2[6], c3[6], c4[12];
  #pragma unroll
  for (int j = 0; j < 6; ++j) {
    e2[j] = h2splat(2.f * ft.f[2 * j]);
    o2[j] = h2splat(2.f * ft.f[2 * j + 1]);
    h2 c; c[0] = (_Float16)(2.f * ft.f[2 * j + 1]); c[1] = (_Float16)(2.f * ft.f[2 * j]);
    c3[j] = c;
  }
  #pragma unroll
  for (int j = 0; j < 12; ++j) c4[j] = h2splat(ft.f[j]);
  const h2 k02 = h2splat(0.2f);
  const h2 ks2 = h2splat(1.41421356237f);
  const h2 kpc = h2splat(256.f);
  const h2 knc = h2splat(-256.f);

  // phase 1: bufY [78][56] fp16; rows 6..71 = y rows 0..65; cols c0-4..c0+21
  #pragma unroll
  for (int p = 0; p < 2; ++p) {
    int e = p * 256 + t;
    if (e < 312) {
      int rp = e >> 2, cg = e & 3;
      int r = rp - 6;
      int cbase = c0 - 4 + 8 * cg;
      uint4 pk = make_uint4(0u, 0u, 0u, 0u);
      if (r >= 0 && r < 66) {
        if (cg < 3 && cbase >= 0 && cbase + 7 <= 65) {
          pk = *(const uint4*)(ysrc + r * 66 + cbase);
        } else {
          unsigned v[8];
          #pragma unroll
          for (int k = 0; k < 8; ++k) {
            int lc = 8 * cg + k, c = c0 - 4 + lc;
            v[k] = (lc < 26 && c >= 0 && c < 66) ? (unsigned)ysrc[r * 66 + c] : 0u;
          }
          pk.x = v[0] | (v[1] << 16); pk.y = v[2] | (v[3] << 16);
          pk.z = v[4] | (v[5] << 16); pk.w = v[6] | (v[7] << 16);
        }
      }
      *(uint4*)(bufYs + rp * 56 + 8 * cg) = pk;
    }
  }
  __syncthreads();

  // phase 2: vertical up-FIR, row pairs -> t1 [138][40]
  #pragma unroll
  for (int p = 0; p < 2; ++p) {
    int e = p * 256 + t;
    if (e < 276) {
      int rq = e >> 2, cg = e & 3;
      const short* base = bufYs + (rq + 2) * 56 + 8 * cg;
      h2 a0[4], a1[4];
      #pragma unroll
      for (int k = 0; k < 4; ++k) { a0[k] = z2; a1[k] = z2; }
      #pragma unroll
      for (int j = 0; j < 6; ++j) {
        uint4 u = *(const uint4*)(base + j * 56);
        h2 v0 = h2bc(u.x), v1 = h2bc(u.y), v2 = h2bc(u.z), v3 = h2bc(u.w);
        a0[0] = v0 * o2[j] + a0[0]; a1[0] = v0 * e2[j] + a1[0];
        a0[1] = v1 * o2[j] + a0[1]; a1[1] = v1 * e2[j] + a1[1];
        a0[2] = v2 * o2[j] + a0[2]; a1[2] = v2 * e2[j] + a1[2];
        a0[3] = v3 * o2[j] + a0[3]; a1[3] = v3 * e2[j] + a1[3];
      }
      uint4 s0, s1;
      s0.x = u32bc(a0[0]); s0.y = u32bc(a0[1]); s0.z = u32bc(a0[2]); s0.w = u32bc(a0[3]);
      s1.x = u32bc(a1[0]); s1.y = u32bc(a1[1]); s1.z = u32bc(a1[2]); s1.w = u32bc(a1[3]);
      *(uint4*)(t1s + (2 * rq) * 40 + 8 * cg) = s0;
      *(uint4*)(t1s + (2 * rq + 1) * 40 + 8 * cg) = s1;
    }
  }
  __syncthreads();

  // phase 3: horizontal up-FIR + lrelu*sqrt2 + clamp -> t2 [138][56]
  #pragma unroll
  for (int p = 0; p < 4; ++p) {
    int e = p * 256 + t;
    if (e < 828) {
      int rr = e / 6, g = e - rr * 6;
      const short* tr = t1s + rr * 40 + 4 * g;
      h2 h[5];
      #pragma unroll
      for (int q = 0; q < 5; ++q) h[q] = h2bc(*(const unsigned*)(tr + 2 * q));
      h2 r[4];
      #pragma unroll
      for (int i = 0; i < 4; ++i) {
        h2 a = z2;
        #pragma unroll
        for (int j = 0; j < 6; ++j) {
          int k = i + j;
          h2 src = h[k >> 1];
          h2 wb = (k & 1) ? __builtin_shufflevector(src, src, 1, 1)
                          : __builtin_shufflevector(src, src, 0, 0);
          a = wb * c3[j] + a;
        }
        h2 m = __builtin_elementwise_max(a, a * k02);
        m = m * ks2;
        m = __builtin_elementwise_min(__builtin_elementwise_max(m, knc), kpc);
        r[i] = m;
      }
      uint4 s;
      s.x = u32bc(r[0]); s.y = u32bc(r[1]); s.z = u32bc(r[2]); s.w = u32bc(r[3]);
      *(uint4*)(t2s + rr * 56 + 8 * g) = s;
    }
  }
  __syncthreads();

  // phase 4: vertical down-FIR (stride 2) -> t3 [64][56]
  #pragma unroll
  for (int p = 0; p < 2; ++p) {
    int e = p * 256 + t;
    if (e < 384) {
      int pp = e / 6, cg = e - pp * 6;
      const short* col = t2s + (2 * pp) * 56 + 8 * cg;
      h2 a[4];
      #pragma unroll
      for (int k = 0; k < 4; ++k) a[k] = z2;
      #pragma unroll
      for (int j = 0; j < 12; ++j) {
        uint4 u = *(const uint4*)(col + j * 56);
        a[0] = h2bc(u.x) * c4[j] + a[0];
        a[1] = h2bc(u.y) * c4[j] + a[1];
        a[2] = h2bc(u.z) * c4[j] + a[2];
        a[3] = h2bc(u.w) * c4[j] + a[3];
      }
      uint4 s;
      s.x = u32bc(a[0]); s.y = u32bc(a[1]); s.z = u32bc(a[2]); s.w = u32bc(a[3]);
      *(uint4*)(t3s + pp * 56 + 8 * cg) = s;
    }
  }
  __syncthreads();

  // phase 5: horizontal down-FIR (stride 2) + store f32, 4 outs/thread
  {
    int pp = t >> 2, v = t & 3;
    const short* row = t3s + pp * 56 + 8 * v;
    h2 h[9];
    #pragma unroll
    for (int q = 0; q < 9; ++q) h[q] = h2bc(*(const unsigned*)(row + 2 * q));
    h2 aA = z2, aB = z2;
    #pragma unroll
    for (int j = 0; j < 12; ++j) {
      int q = j >> 1;
      h2 wA = (j & 1) ? __builtin_shufflevector(h[q], h[q + 1], 1, 3)
                      : __builtin_shufflevector(h[q], h[q + 1], 0, 2);
      h2 wB = (j & 1) ? __builtin_shufflevector(h[q + 2], h[q + 3], 1, 3)
                      : __builtin_shufflevector(h[q + 2], h[q + 3], 0, 2);
      aA = wA * c4[j] + aA;
      aB = wB * c4[j] + aB;
    }
    *(float4*)&out[img * 4096 + pp * 64 + c0 + 4 * v] =
        make_float4((float)aA[0], (float)aA[1], (float)aB[0], (float)aB[1]);
  }
}

// ---------- host ----------
static double bessel_i0(double x) {
  double q = x * x * 0.25, term = 1.0, sum = 1.0;
  for (int k = 1; k < 64; ++k) {
    term *= q / ((double)k * (double)k);
    sum += term;
    if (term < sum * 1e-18) break;
  }
  return sum;
}

extern "C" void kernel_launch(void* const* d_in, const int* in_sizes, int n_in,
                              void* d_out, int out_size, void* d_ws, size_t ws_size,
                              hipStream_t stream) {
  const float* x   = (const float*)d_in[0];
  const float* w   = (const float*)d_in[1];
  const float* aw  = (const float*)d_in[2];
  const float* ab  = (const float*)d_in[3];
  const float* cw  = (const float*)d_in[4];
  const float* cb  = (const float*)d_in[5];
  const float* ema = (const float*)d_in[6];
  float* out = (float*)d_out;
  char* ws = (char*)d_ws;

  float* styles        = (float*)(ws + 0);          // 16 KB
  float* scal          = (float*)(ws + 16384);      // 16 B
  float* wsq           = (float*)(ws + 16640);      // 256 KB
  float* dco           = (float*)(ws + 278784);     // 16 KB
  __hip_bfloat16* wbt  = (__hip_bfloat16*)(ws + 295168);   // 1.18 MB  [9][256][256]
  unsigned short* xp   = (unsigned short*)(ws + 1474816);  // 37.9 MB  [16][68][68][256]
  unsigned short* y    = (unsigned short*)(ws + 39354624); // 35.7 MB  [16][256][66][66] fp16

  // firwin(12, 16, width=32, fs=128) with Kaiser window (double precision)
  Filt ft;
  {
    double atten = 2.285 * 11.0 * M_PI * 0.5 + 7.95;
    double beta;
    if (atten > 50.0) beta = 0.1102 * (atten - 8.7);
    else if (atten > 21.0) beta = 0.5842 * pow(atten - 21.0, 0.4) + 0.07886 * (atten - 21.0);
    else beta = 0.0;
    double i0b = bessel_i0(beta);
    double h[12], ssum = 0.0;
    for (int n = 0; n < 12; ++n) {
      double xx = ((double)n - 5.5) / 5.5;
      double win = bessel_i0(beta * sqrt(1.0 - xx * xx)) / i0b;
      double mm = ((double)n - 5.5) * 0.25;
      double snc = sin(M_PI * mm) / (M_PI * mm);
      h[n] = 0.25 * snc * win;
      ssum += h[n];
    }
    for (int n = 0; n < 12; ++n) ft.f[n] = (float)(h[n] / ssum);
  }

  k_styles <<<16, 256, 0, stream>>>(w, aw, ab, styles);
  k_scalars<<<1, 256, 0, stream>>>(styles, ema, scal);
  k_wnorm  <<<256, 256, 0, stream>>>(cw, wsq, wbt);
  k_dcoefs <<<16, 256, 0, stream>>>(styles, wsq, scal, dco);
  k_xpad   <<<dim3(4, 68, 16), 256, 0, stream>>>(x, styles, scal, xp);
  k_conv   <<<2180, 256, 0, stream>>>(xp, (const unsigned short*)wbt, dco, cb, y);
  k_lrelu  <<<16384, 256, 0, stream>>>(y, out, ft);
}